// Round 3
// baseline (1905.906 us; speedup 1.0000x reference)
//
#include <hip/hip_runtime.h>
#include <hip/hip_bf16.h>

typedef __hip_bfloat16 bf16;

// Problem constants: B=2, T=4, H=W=64, C=256, ws=8
// N = 128 windows, L = 256 tokens, C = 256, heads = 8, head_dim = 32
#define SCALE_F 0.17677669529663687f
#define EPS_F 1e-5f
#define NW_CHUNK 32                 // windows per pipeline chunk (4 chunks)
#define ROWS_CHUNK (NW_CHUNK * 256) // 8192 token-rows per chunk

__device__ __forceinline__ float b2f(bf16 v) { return __bfloat162float(v); }
__device__ __forceinline__ bf16 f2b(float v) { return __float2bfloat16(v); }

// Load input element i as float. mode=1: buffer is fp32. mode=0: bf16.
// NOTE: the fp32 load is kept behind a real branch — when the buffer is bf16,
// a fp32-indexed load at i >= n/2 would be OOB, so it must not be speculated.
__device__ __forceinline__ float ldin(const void* p, size_t i, int mode) {
  if (mode) return ((const float*)p)[i];
  return b2f(((const bf16*)p)[i]);
}
__device__ __forceinline__ void stout(void* p, size_t i, int mode, float v) {
  if (mode) ((float*)p)[i] = v;
  else      ((bf16*)p)[i] = f2b(v);
}

// ---------------------------------------------------------------------------
// Probe: classify input dtype. bf16 data reinterpreted as fp32 words has
// exponent bits taken from bf16 exponent/mantissa interiors -> |v| >~ 1e29 or
// Inf/NaN for essentially every word. Genuine fp32 N(0,1) is always < 1e20.
// ---------------------------------------------------------------------------
__global__ __launch_bounds__(256) void k_probe(const float* __restrict__ xf,
                                               int* __restrict__ flag) {
  __shared__ int cnt;
  if (threadIdx.x == 0) cnt = 0;
  __syncthreads();
  int bad = 0;
  for (int i = threadIdx.x; i < 1024; i += 256) {
    const float v = xf[i];            // in-bounds under either dtype (4 KiB)
    if (!(fabsf(v) < 1e20f)) bad++;   // NaN/Inf/huge all count as bad
  }
  atomicAdd(&cnt, bad);
  __syncthreads();
  if (threadIdx.x == 0) flag[0] = (cnt < 8) ? 1 : 0;  // 1 = fp32 inputs
}

// ---------------------------------------------------------------------------
// Kernel 1: gather x -> window layout, LayerNorm over C, write xn (N*L, C) bf16
// ---------------------------------------------------------------------------
__global__ __launch_bounds__(256) void k_ln(const void* __restrict__ x,
                                            const void* __restrict__ gamma,
                                            const void* __restrict__ beta,
                                            bf16* __restrict__ xn,
                                            const int* __restrict__ flag) {
  const int mode = flag[0];
  const int blk = blockIdx.x;
  const int n = blk >> 8, l = blk & 255;
  const int b = n >> 6, ih = (n >> 3) & 7, iw = n & 7;
  const int t = l >> 6, r = (l >> 3) & 7, s = l & 7;
  const int bt = b * 4 + t;
  const int h = ih * 8 + r, w = iw * 8 + s;
  const int c = threadIdx.x;
  const float val = ldin(x, (((size_t)bt * 256 + c) * 64 + h) * 64 + w, mode);

  float s1 = val, s2 = val * val;
#pragma unroll
  for (int off = 32; off > 0; off >>= 1) {
    s1 += __shfl_down(s1, off, 64);
    s2 += __shfl_down(s2, off, 64);
  }
  __shared__ float red[8];
  const int wid = threadIdx.x >> 6;
  if ((threadIdx.x & 63) == 0) { red[wid] = s1; red[4 + wid] = s2; }
  __syncthreads();
  if (threadIdx.x == 0) {
    float a = red[0] + red[1] + red[2] + red[3];
    float q = red[4] + red[5] + red[6] + red[7];
    float mu = a * (1.0f / 256.0f);
    float var = fmaxf(q * (1.0f / 256.0f) - mu * mu, 0.0f);
    red[0] = mu;
    red[1] = rsqrtf(var + EPS_F);
  }
  __syncthreads();
  const float mu = red[0], rs = red[1];
  const float o = (val - mu) * rs * ldin(gamma, c, mode) + ldin(beta, c, mode);
  xn[(size_t)blk * 256 + c] = f2b(o);
}

// ---------------------------------------------------------------------------
// Kernel 2: qkv_chunk = xn[row_base .. row_base+8191] @ w_qkv^T + b_qkv
// out chunk-local (8192 x 768) bf16. 64x64 tiles, 4x4 per thread, fp32 acc.
// ---------------------------------------------------------------------------
__global__ __launch_bounds__(256) void k_qkv(const bf16* __restrict__ A,
                                             const void* __restrict__ Wt,
                                             const void* __restrict__ bias,
                                             bf16* __restrict__ out,
                                             int row_base,
                                             const int* __restrict__ flag) {
  const int mode = flag[0];
  __shared__ float sA[64][65];
  __shared__ float sB[64][65];
  const int row0 = blockIdx.x * 64;   // chunk-local
  const int col0 = blockIdx.y * 64;
  const int tid = threadIdx.x;
  const int tx = tid & 15, ty = tid >> 4;
  float acc[4][4] = {};

  for (int k0 = 0; k0 < 256; k0 += 64) {
    for (int i = tid; i < 4096; i += 256) {
      const int rr = i >> 6, cc = i & 63;
      sA[rr][cc] = b2f(A[(size_t)(row_base + row0 + rr) * 256 + k0 + cc]);
      sB[rr][cc] = ldin(Wt, (size_t)(col0 + rr) * 256 + k0 + cc, mode);
    }
    __syncthreads();
#pragma unroll 8
    for (int kk = 0; kk < 64; ++kk) {
      float a[4], bb[4];
#pragma unroll
      for (int i = 0; i < 4; ++i) a[i] = sA[ty * 4 + i][kk];
#pragma unroll
      for (int j = 0; j < 4; ++j) bb[j] = sB[tx * 4 + j][kk];
#pragma unroll
      for (int i = 0; i < 4; ++i)
#pragma unroll
        for (int j = 0; j < 4; ++j) acc[i][j] += a[i] * bb[j];
    }
    __syncthreads();
  }

#pragma unroll
  for (int j = 0; j < 4; ++j) {
    const int col = col0 + tx * 4 + j;
    const float bj = ldin(bias, col, mode);
#pragma unroll
    for (int i = 0; i < 4; ++i) {
      const size_t row = (size_t)(row0 + ty * 4 + i);
      out[row * 768 + col] = f2b(acc[i][j] + bj);
    }
  }
}

// ---------------------------------------------------------------------------
// Kernel 3: attention per (window, head) within a chunk. Reads chunk-local
// qkv (bf16); writes to GLOBAL rows of aout (overwriting dead xn rows).
// ---------------------------------------------------------------------------
__global__ __launch_bounds__(256) void k_attn(const bf16* __restrict__ qkv,
                                              bf16* __restrict__ aout,
                                              int n_base) {
  const int n_loc = blockIdx.x >> 3, hh = blockIdx.x & 7;
  const int n_glob = n_base + n_loc;
  __shared__ bf16 sK[256][34];
  __shared__ bf16 sV[256][34];
  __shared__ float sS[16][260];
  __shared__ float sQ[16][33];
  const size_t base = (size_t)n_loc * 256 * 768;
  const int tid = threadIdx.x;
  const int wid = tid >> 6, lid = tid & 63;

  for (int i = tid; i < 256 * 32; i += 256) {
    const int m = i >> 5, d = i & 31;
    sK[m][d] = qkv[base + (size_t)m * 768 + 256 + hh * 32 + d];
    sV[m][d] = qkv[base + (size_t)m * 768 + 512 + hh * 32 + d];
  }
  __syncthreads();

  for (int l0 = 0; l0 < 256; l0 += 16) {
    for (int i = tid; i < 16 * 32; i += 256) {
      const int li = i >> 5, d = i & 31;
      sQ[li][d] = SCALE_F * b2f(qkv[base + (size_t)(l0 + li) * 768 + hh * 32 + d]);
    }
    __syncthreads();

    {
      const int li = tid >> 4;
      const int mb = tid & 15;
#pragma unroll
      for (int e = 0; e < 16; ++e) {
        const int m = mb + e * 16;
        float acc = 0.f;
#pragma unroll
        for (int d = 0; d < 32; ++d) acc += sQ[li][d] * b2f(sK[m][d]);
        sS[li][m] = acc;
      }
    }
    __syncthreads();

    for (int qq = 0; qq < 4; ++qq) {
      const int li = wid * 4 + qq;
      float4 vv = *(const float4*)&sS[li][lid * 4];
      float mx = fmaxf(fmaxf(vv.x, vv.y), fmaxf(vv.z, vv.w));
#pragma unroll
      for (int off = 32; off > 0; off >>= 1) mx = fmaxf(mx, __shfl_down(mx, off, 64));
      mx = __shfl(mx, 0, 64);
      vv.x = __expf(vv.x - mx); vv.y = __expf(vv.y - mx);
      vv.z = __expf(vv.z - mx); vv.w = __expf(vv.w - mx);
      float sm = vv.x + vv.y + vv.z + vv.w;
#pragma unroll
      for (int off = 32; off > 0; off >>= 1) sm += __shfl_down(sm, off, 64);
      sm = __shfl(sm, 0, 64);
      const float inv = 1.0f / sm;
      vv.x *= inv; vv.y *= inv; vv.z *= inv; vv.w *= inv;
      *(float4*)&sS[li][lid * 4] = vv;
    }
    __syncthreads();

    {
      const int li = tid >> 4;
      const int d0 = tid & 15, d1 = d0 + 16;
      float a0 = 0.f, a1 = 0.f;
      for (int m = 0; m < 256; ++m) {
        const float p = sS[li][m];
        a0 += p * b2f(sV[m][d0]);
        a1 += p * b2f(sV[m][d1]);
      }
      const size_t orow = ((size_t)n_glob * 256 + l0 + li) * 256 + hh * 32;
      aout[orow + d0] = f2b(a0);
      aout[orow + d1] = f2b(a1);
    }
    __syncthreads();
  }
}

// ---------------------------------------------------------------------------
// Kernel 4: proj GEMM (32768x256 @ 256x256) + bias + residual + scatter
// ---------------------------------------------------------------------------
__global__ __launch_bounds__(256) void k_proj(const bf16* __restrict__ A,
                                              const void* __restrict__ Wp,
                                              const void* __restrict__ bias,
                                              const void* __restrict__ x,
                                              void* __restrict__ out,
                                              const int* __restrict__ flag) {
  const int mode = flag[0];
  __shared__ float sA[64][65];
  __shared__ float sB[64][65];
  const int row0 = blockIdx.x * 64;
  const int col0 = blockIdx.y * 64;
  const int tid = threadIdx.x;
  const int tx = tid & 15, ty = tid >> 4;
  float acc[4][4] = {};

  for (int k0 = 0; k0 < 256; k0 += 64) {
    for (int i = tid; i < 4096; i += 256) {
      const int rr = i >> 6, cc = i & 63;
      sA[rr][cc] = b2f(A[(size_t)(row0 + rr) * 256 + k0 + cc]);
      sB[rr][cc] = ldin(Wp, (size_t)(col0 + rr) * 256 + k0 + cc, mode);
    }
    __syncthreads();
#pragma unroll 8
    for (int kk = 0; kk < 64; ++kk) {
      float a[4], bb[4];
#pragma unroll
      for (int i = 0; i < 4; ++i) a[i] = sA[ty * 4 + i][kk];
#pragma unroll
      for (int j = 0; j < 4; ++j) bb[j] = sB[tx * 4 + j][kk];
#pragma unroll
      for (int i = 0; i < 4; ++i)
#pragma unroll
        for (int j = 0; j < 4; ++j) acc[i][j] += a[i] * bb[j];
    }
    __syncthreads();
  }

#pragma unroll
  for (int i = 0; i < 4; ++i) {
    const int row = row0 + ty * 4 + i;  // n*256 + l
    const int n = row >> 8, l = row & 255;
    const int b = n >> 6, ih = (n >> 3) & 7, iw = n & 7;
    const int t = l >> 6, r = (l >> 3) & 7, s = l & 7;
    const int bt = b * 4 + t;
    const int h = ih * 8 + r, w = iw * 8 + s;
#pragma unroll
    for (int j = 0; j < 4; ++j) {
      const int c = col0 + tx * 4 + j;
      const size_t gaddr = (((size_t)bt * 256 + c) * 64 + h) * 64 + w;
      const float o = acc[i][j] + ldin(bias, c, mode) + ldin(x, gaddr, mode);
      stout(out, gaddr, mode, o);
    }
  }
}

// ---------------------------------------------------------------------------
extern "C" void kernel_launch(void* const* d_in, const int* in_sizes, int n_in,
                              void* d_out, int out_size, void* d_ws, size_t ws_size,
                              hipStream_t stream) {
  (void)in_sizes; (void)n_in; (void)out_size; (void)ws_size;
  const void* x      = d_in[0];
  const void* w_qkv  = d_in[1];
  const void* b_qkv  = d_in[2];
  const void* w_proj = d_in[3];
  const void* b_proj = d_in[4];
  const void* gamma  = d_in[5];
  const void* beta   = d_in[6];

  char* ws = (char*)d_ws;
  int* flag   = (int*)ws;                               // 4 B (+pad to 1 KiB)
  bf16* xnbuf = (bf16*)(ws + 1024);                     // 32768*256*2 = 16 MiB
  bf16* qkvc  = (bf16*)(ws + 1024 + (size_t)16777216);  // 8192*768*2 = 12.6 MiB

  hipLaunchKernelGGL(k_probe, dim3(1), dim3(256), 0, stream, (const float*)x, flag);
  hipLaunchKernelGGL(k_ln, dim3(32768), dim3(256), 0, stream, x, gamma, beta, xnbuf, flag);
  for (int c = 0; c < 4; ++c) {
    hipLaunchKernelGGL(k_qkv, dim3(128, 12), dim3(256), 0, stream,
                       xnbuf, w_qkv, b_qkv, qkvc, c * ROWS_CHUNK, flag);
    hipLaunchKernelGGL(k_attn, dim3(NW_CHUNK * 8), dim3(256), 0, stream,
                       qkvc, xnbuf, c * NW_CHUNK);
  }
  hipLaunchKernelGGL(k_proj, dim3(512, 4), dim3(256), 0, stream,
                     xnbuf, w_proj, b_proj, x, d_out, flag);
}

// Round 5
// 709.000 us; speedup vs baseline: 2.6882x; 2.6882x over previous
//
#include <hip/hip_runtime.h>
#include <hip/hip_bf16.h>

typedef __hip_bfloat16 bf16;
typedef __attribute__((ext_vector_type(8))) short short8;   // 8 bf16 bits (4 VGPRs)
typedef __attribute__((ext_vector_type(4))) float f32x4;    // MFMA C/D

// Problem constants: B=2, T=4, H=W=64, C=256, ws=8
// N = 128 windows, L = 256 tokens, C = 256, heads = 8, head_dim = 32
#define SCALE_F 0.17677669529663687f
#define LOG2E_F 1.4426950408889634f
#define EPS_F 1e-5f
#define NW_CHUNK 32                 // windows per pipeline chunk (4 chunks)
#define ROWS_CHUNK (NW_CHUNK * 256) // 8192 token-rows per chunk

__device__ __forceinline__ float b2f(bf16 v) { return __bfloat162float(v); }
__device__ __forceinline__ bf16 f2b(float v) { return __float2bfloat16(v); }
__device__ __forceinline__ short f2bs(float v) { bf16 h = f2b(v); return *(short*)&h; }

// Load input element i as float. mode=1: buffer is fp32. mode=0: bf16.
__device__ __forceinline__ float ldin(const void* p, size_t i, int mode) {
  if (mode) return ((const float*)p)[i];
  return b2f(((const bf16*)p)[i]);
}
__device__ __forceinline__ void stout(void* p, size_t i, int mode, float v) {
  if (mode) ((float*)p)[i] = v;
  else      ((bf16*)p)[i] = f2b(v);
}

// ---------------------------------------------------------------------------
// Probe: classify input dtype (1 = fp32, 0 = bf16). See R2 notes.
// ---------------------------------------------------------------------------
__global__ __launch_bounds__(256) void k_probe(const float* __restrict__ xf,
                                               int* __restrict__ flag) {
  __shared__ int cnt;
  if (threadIdx.x == 0) cnt = 0;
  __syncthreads();
  int bad = 0;
  for (int i = threadIdx.x; i < 1024; i += 256) {
    const float v = xf[i];
    if (!(fabsf(v) < 1e20f)) bad++;
  }
  atomicAdd(&cnt, bad);
  __syncthreads();
  if (threadIdx.x == 0) flag[0] = (cnt < 8) ? 1 : 0;
}

// ---------------------------------------------------------------------------
// Kernel 1: gather x -> window layout, LayerNorm over C, write xn (N*L, C) bf16
// ---------------------------------------------------------------------------
__global__ __launch_bounds__(256) void k_ln(const void* __restrict__ x,
                                            const void* __restrict__ gamma,
                                            const void* __restrict__ beta,
                                            bf16* __restrict__ xn,
                                            const int* __restrict__ flag) {
  const int mode = flag[0];
  const int blk = blockIdx.x;
  const int n = blk >> 8, l = blk & 255;
  const int b = n >> 6, ih = (n >> 3) & 7, iw = n & 7;
  const int t = l >> 6, r = (l >> 3) & 7, s = l & 7;
  const int bt = b * 4 + t;
  const int h = ih * 8 + r, w = iw * 8 + s;
  const int c = threadIdx.x;
  const float val = ldin(x, (((size_t)bt * 256 + c) * 64 + h) * 64 + w, mode);

  float s1 = val, s2 = val * val;
#pragma unroll
  for (int off = 32; off > 0; off >>= 1) {
    s1 += __shfl_down(s1, off, 64);
    s2 += __shfl_down(s2, off, 64);
  }
  __shared__ float red[8];
  const int wid = threadIdx.x >> 6;
  if ((threadIdx.x & 63) == 0) { red[wid] = s1; red[4 + wid] = s2; }
  __syncthreads();
  if (threadIdx.x == 0) {
    float a = red[0] + red[1] + red[2] + red[3];
    float q = red[4] + red[5] + red[6] + red[7];
    float mu = a * (1.0f / 256.0f);
    float var = fmaxf(q * (1.0f / 256.0f) - mu * mu, 0.0f);
    red[0] = mu;
    red[1] = rsqrtf(var + EPS_F);
  }
  __syncthreads();
  const float mu = red[0], rs = red[1];
  const float o = (val - mu) * rs * ldin(gamma, c, mode) + ldin(beta, c, mode);
  xn[(size_t)blk * 256 + c] = f2b(o);
}

// ---------------------------------------------------------------------------
// Kernel 2: qkv_chunk = xn[row_base..+8191] @ w_qkv^T + b_qkv -> bf16 chunk
// ---------------------------------------------------------------------------
__global__ __launch_bounds__(256) void k_qkv(const bf16* __restrict__ A,
                                             const void* __restrict__ Wt,
                                             const void* __restrict__ bias,
                                             bf16* __restrict__ out,
                                             int row_base,
                                             const int* __restrict__ flag) {
  const int mode = flag[0];
  __shared__ float sA[64][65];
  __shared__ float sB[64][65];
  const int row0 = blockIdx.x * 64;   // chunk-local
  const int col0 = blockIdx.y * 64;
  const int tid = threadIdx.x;
  const int tx = tid & 15, ty = tid >> 4;
  float acc[4][4] = {};

  for (int k0 = 0; k0 < 256; k0 += 64) {
    for (int i = tid; i < 4096; i += 256) {
      const int rr = i >> 6, cc = i & 63;
      sA[rr][cc] = b2f(A[(size_t)(row_base + row0 + rr) * 256 + k0 + cc]);
      sB[rr][cc] = ldin(Wt, (size_t)(col0 + rr) * 256 + k0 + cc, mode);
    }
    __syncthreads();
#pragma unroll 8
    for (int kk = 0; kk < 64; ++kk) {
      float a[4], bb[4];
#pragma unroll
      for (int i = 0; i < 4; ++i) a[i] = sA[ty * 4 + i][kk];
#pragma unroll
      for (int j = 0; j < 4; ++j) bb[j] = sB[tx * 4 + j][kk];
#pragma unroll
      for (int i = 0; i < 4; ++i)
#pragma unroll
        for (int j = 0; j < 4; ++j) acc[i][j] += a[i] * bb[j];
    }
    __syncthreads();
  }

#pragma unroll
  for (int j = 0; j < 4; ++j) {
    const int col = col0 + tx * 4 + j;
    const float bj = ldin(bias, col, mode);
#pragma unroll
    for (int i = 0; i < 4; ++i) {
      const size_t row = (size_t)(row0 + ty * 4 + i);
      out[row * 768 + col] = f2b(acc[i][j] + bj);
    }
  }
}

// ---------------------------------------------------------------------------
// Kernel 3: MFMA attention, one block per (window, head). 4 waves; wave wid
// owns Q-rows [wid*64, wid*64+64). Layouts (m89/m120 verified):
//   A-frag  A[m=lane&15][k=quad*8+j]
//   B-frag  B[n=lane&15][k=quad*8+j]
//   C/D     col=lane&15, row=quad*4+reg
// Softmax fully in registers (shfl_xor over low 4 lane bits). P round-trips
// LDS per-wave in two 128-col halves; 1/rowsum applied at the O epilogue.
// ---------------------------------------------------------------------------
__global__ __launch_bounds__(256) void k_attn(const bf16* __restrict__ qkv,
                                              bf16* __restrict__ aout,
                                              int n_base) {
  const int n_loc = blockIdx.x >> 3, hh = blockIdx.x & 7;
  const int n_glob = n_base + n_loc;
  __shared__ short sK[256][40];     // K[m][d], +8 pad (16B-aligned rows)
  __shared__ short sVt[32][264];    // V^T[d][m], +8 pad
  __shared__ short sP[4][16][136];  // per-wave P half-slab [l][m_local], +8 pad
  const int tid = threadIdx.x;
  const int wid = tid >> 6, lane = tid & 63;
  const int l15 = lane & 15, quad = lane >> 4;
  const short* qg = (const short*)qkv;
  const size_t base = (size_t)n_loc * 256 * 768 + hh * 32;

  // Stage K and V^T into LDS. 256 rows x 32 dims = 1024 short8 chunks each.
  // (R4 bug: loop only covered 512 chunks -> d in [0,16) and NaN from
  //  uninitialized LDS. Now m = c>>2, d0 = (c&3)*8 covers d in [0,32).)
  for (int c = tid; c < 1024; c += 256) {
    const int m = c >> 2, d0 = (c & 3) * 8;
    *(short8*)&sK[m][d0] = *(const short8*)(qg + base + (size_t)m * 768 + 256 + d0);
    short8 vv = *(const short8*)(qg + base + (size_t)m * 768 + 512 + d0);
#pragma unroll
    for (int j = 0; j < 8; ++j) sVt[d0 + j][m] = vv[j];
  }
  __syncthreads();

  const int R0 = wid * 64;
  const float esc = SCALE_F * LOG2E_F;

  for (int lt = 0; lt < 4; ++lt) {
    const int lrow = R0 + lt * 16;
    // Q A-frag straight from global (aligned 16B)
    const short8 qf = *(const short8*)(qg + base + (size_t)(lrow + l15) * 768 + quad * 8);

    // S = Q K^T : 16 column tiles accumulated in registers
    f32x4 sacc[16];
#pragma unroll
    for (int t = 0; t < 16; ++t) {
      sacc[t] = (f32x4){0.f, 0.f, 0.f, 0.f};
      const short8 kf = *(const short8*)&sK[t * 16 + l15][quad * 8];
      sacc[t] = __builtin_amdgcn_mfma_f32_16x16x32_bf16(qf, kf, sacc[t], 0, 0, 0);
    }

    // In-register softmax over rows (row = quad*4+r; cols spread over l15,t)
    float mx[4] = {-3.0e38f, -3.0e38f, -3.0e38f, -3.0e38f};
#pragma unroll
    for (int t = 0; t < 16; ++t)
#pragma unroll
      for (int r = 0; r < 4; ++r) mx[r] = fmaxf(mx[r], sacc[t][r]);
#pragma unroll
    for (int m = 1; m < 16; m <<= 1)
#pragma unroll
      for (int r = 0; r < 4; ++r) mx[r] = fmaxf(mx[r], __shfl_xor(mx[r], m, 64));
    float sum[4] = {0.f, 0.f, 0.f, 0.f};
#pragma unroll
    for (int t = 0; t < 16; ++t)
#pragma unroll
      for (int r = 0; r < 4; ++r) {
        const float p = exp2f((sacc[t][r] - mx[r]) * esc);
        sacc[t][r] = p;
        sum[r] += p;
      }
#pragma unroll
    for (int m = 1; m < 16; m <<= 1)
#pragma unroll
      for (int r = 0; r < 4; ++r) sum[r] += __shfl_xor(sum[r], m, 64);
    float inv[4];
#pragma unroll
    for (int r = 0; r < 4; ++r) inv[r] = 1.0f / sum[r];

    // O = P V in two 128-col halves through per-wave LDS slab
    f32x4 oacc[2] = {(f32x4){0.f, 0.f, 0.f, 0.f}, (f32x4){0.f, 0.f, 0.f, 0.f}};
    for (int half = 0; half < 2; ++half) {
      __syncthreads();  // prev reads of sP complete (WAR)
#pragma unroll
      for (int t = 0; t < 8; ++t) {
        const int tt = half * 8 + t;
#pragma unroll
        for (int r = 0; r < 4; ++r)
          sP[wid][quad * 4 + r][t * 16 + l15] = f2bs(sacc[tt][r]);
      }
      __syncthreads();  // writes visible (RAW)
#pragma unroll
      for (int kk = 0; kk < 4; ++kk) {
        const short8 pf = *(const short8*)&sP[wid][l15][kk * 32 + quad * 8];
#pragma unroll
        for (int dt = 0; dt < 2; ++dt) {
          const short8 vf =
              *(const short8*)&sVt[dt * 16 + l15][half * 128 + kk * 32 + quad * 8];
          oacc[dt] = __builtin_amdgcn_mfma_f32_16x16x32_bf16(pf, vf, oacc[dt], 0, 0, 0);
        }
      }
    }

    // Epilogue: normalize by row sums and store (C/D: row=quad*4+r, col=l15)
#pragma unroll
    for (int dt = 0; dt < 2; ++dt)
#pragma unroll
      for (int r = 0; r < 4; ++r) {
        const int l = lrow + quad * 4 + r;
        aout[((size_t)n_glob * 256 + l) * 256 + hh * 32 + dt * 16 + l15] =
            f2b(oacc[dt][r] * inv[r]);
      }
  }
}

// ---------------------------------------------------------------------------
// Kernel 4: proj GEMM (32768x256 @ 256x256) + bias + residual + scatter
// ---------------------------------------------------------------------------
__global__ __launch_bounds__(256) void k_proj(const bf16* __restrict__ A,
                                              const void* __restrict__ Wp,
                                              const void* __restrict__ bias,
                                              const void* __restrict__ x,
                                              void* __restrict__ out,
                                              const int* __restrict__ flag) {
  const int mode = flag[0];
  __shared__ float sA[64][65];
  __shared__ float sB[64][65];
  const int row0 = blockIdx.x * 64;
  const int col0 = blockIdx.y * 64;
  const int tid = threadIdx.x;
  const int tx = tid & 15, ty = tid >> 4;
  float acc[4][4] = {};

  for (int k0 = 0; k0 < 256; k0 += 64) {
    for (int i = tid; i < 4096; i += 256) {
      const int rr = i >> 6, cc = i & 63;
      sA[rr][cc] = b2f(A[(size_t)(row0 + rr) * 256 + k0 + cc]);
      sB[rr][cc] = ldin(Wp, (size_t)(col0 + rr) * 256 + k0 + cc, mode);
    }
    __syncthreads();
#pragma unroll 8
    for (int kk = 0; kk < 64; ++kk) {
      float a[4], bb[4];
#pragma unroll
      for (int i = 0; i < 4; ++i) a[i] = sA[ty * 4 + i][kk];
#pragma unroll
      for (int j = 0; j < 4; ++j) bb[j] = sB[tx * 4 + j][kk];
#pragma unroll
      for (int i = 0; i < 4; ++i)
#pragma unroll
        for (int j = 0; j < 4; ++j) acc[i][j] += a[i] * bb[j];
    }
    __syncthreads();
  }

#pragma unroll
  for (int i = 0; i < 4; ++i) {
    const int row = row0 + ty * 4 + i;  // n*256 + l
    const int n = row >> 8, l = row & 255;
    const int b = n >> 6, ih = (n >> 3) & 7, iw = n & 7;
    const int t = l >> 6, r = (l >> 3) & 7, s = l & 7;
    const int bt = b * 4 + t;
    const int h = ih * 8 + r, w = iw * 8 + s;
#pragma unroll
    for (int j = 0; j < 4; ++j) {
      const int c = col0 + tx * 4 + j;
      const size_t gaddr = (((size_t)bt * 256 + c) * 64 + h) * 64 + w;
      const float o = acc[i][j] + ldin(bias, c, mode) + ldin(x, gaddr, mode);
      stout(out, gaddr, mode, o);
    }
  }
}

// ---------------------------------------------------------------------------
extern "C" void kernel_launch(void* const* d_in, const int* in_sizes, int n_in,
                              void* d_out, int out_size, void* d_ws, size_t ws_size,
                              hipStream_t stream) {
  (void)in_sizes; (void)n_in; (void)out_size; (void)ws_size;
  const void* x      = d_in[0];
  const void* w_qkv  = d_in[1];
  const void* b_qkv  = d_in[2];
  const void* w_proj = d_in[3];
  const void* b_proj = d_in[4];
  const void* gamma  = d_in[5];
  const void* beta   = d_in[6];

  char* ws = (char*)d_ws;
  int* flag   = (int*)ws;                               // 4 B (+pad to 1 KiB)
  bf16* xnbuf = (bf16*)(ws + 1024);                     // 32768*256*2 = 16 MiB
  bf16* qkvc  = (bf16*)(ws + 1024 + (size_t)16777216);  // 8192*768*2 = 12.6 MiB

  hipLaunchKernelGGL(k_probe, dim3(1), dim3(256), 0, stream, (const float*)x, flag);
  hipLaunchKernelGGL(k_ln, dim3(32768), dim3(256), 0, stream, x, gamma, beta, xnbuf, flag);
  for (int c = 0; c < 4; ++c) {
    hipLaunchKernelGGL(k_qkv, dim3(128, 12), dim3(256), 0, stream,
                       xnbuf, w_qkv, b_qkv, qkvc, c * ROWS_CHUNK, flag);
    hipLaunchKernelGGL(k_attn, dim3(NW_CHUNK * 8), dim3(256), 0, stream,
                       qkvc, xnbuf, c * NW_CHUNK);
  }
  hipLaunchKernelGGL(k_proj, dim3(512, 4), dim3(256), 0, stream,
                     xnbuf, w_proj, b_proj, x, d_out, flag);
}

// Round 6
// 410.932 us; speedup vs baseline: 4.6380x; 1.7253x over previous
//
#include <hip/hip_runtime.h>
#include <hip/hip_bf16.h>

typedef __hip_bfloat16 bf16;
typedef __attribute__((ext_vector_type(8))) short short8;   // 8 bf16 bits (4 VGPRs)
typedef __attribute__((ext_vector_type(4))) float f32x4;    // MFMA C/D

// Problem constants: B=2, T=4, H=W=64, C=256, ws=8
// N = 128 windows, L = 256 tokens, C = 256, heads = 8, head_dim = 32
#define SCALE_F 0.17677669529663687f
#define LOG2E_F 1.4426950408889634f
#define EPS_F 1e-5f
#define NW_CHUNK 32                 // windows per pipeline chunk (4 chunks)
#define ROWS_CHUNK (NW_CHUNK * 256) // 8192 token-rows per chunk

__device__ __forceinline__ float b2f(bf16 v) { return __bfloat162float(v); }
__device__ __forceinline__ bf16 f2b(float v) { return __float2bfloat16(v); }
__device__ __forceinline__ short f2bs(float v) { bf16 h = f2b(v); return *(short*)&h; }

// Load input element i as float. mode=1: buffer is fp32. mode=0: bf16.
__device__ __forceinline__ float ldin(const void* p, size_t i, int mode) {
  if (mode) return ((const float*)p)[i];
  return b2f(((const bf16*)p)[i]);
}
__device__ __forceinline__ void stout(void* p, size_t i, int mode, float v) {
  if (mode) ((float*)p)[i] = v;
  else      ((bf16*)p)[i] = f2b(v);
}
// Load 8 consecutive elements as bf16 bit-pattern vector (weights staging).
__device__ __forceinline__ short8 ldin8(const void* p, size_t i, int mode) {
  if (mode) {
    const float* f = (const float*)p + i;
    float4 f0 = *(const float4*)f, f1 = *(const float4*)(f + 4);
    short8 r;
    r[0] = f2bs(f0.x); r[1] = f2bs(f0.y); r[2] = f2bs(f0.z); r[3] = f2bs(f0.w);
    r[4] = f2bs(f1.x); r[5] = f2bs(f1.y); r[6] = f2bs(f1.z); r[7] = f2bs(f1.w);
    return r;
  }
  return *(const short8*)((const short*)p + i);
}

// ---------------------------------------------------------------------------
// Probe: classify input dtype (1 = fp32, 0 = bf16). See R2 notes.
// ---------------------------------------------------------------------------
__global__ __launch_bounds__(256) void k_probe(const float* __restrict__ xf,
                                               int* __restrict__ flag) {
  __shared__ int cnt;
  if (threadIdx.x == 0) cnt = 0;
  __syncthreads();
  int bad = 0;
  for (int i = threadIdx.x; i < 1024; i += 256) {
    const float v = xf[i];
    if (!(fabsf(v) < 1e20f)) bad++;
  }
  atomicAdd(&cnt, bad);
  __syncthreads();
  if (threadIdx.x == 0) flag[0] = (cnt < 8) ? 1 : 0;
}

// ---------------------------------------------------------------------------
// Kernel 1: gather x -> window layout, LayerNorm over C, write xn (N*L, C) bf16
// ---------------------------------------------------------------------------
__global__ __launch_bounds__(256) void k_ln(const void* __restrict__ x,
                                            const void* __restrict__ gamma,
                                            const void* __restrict__ beta,
                                            bf16* __restrict__ xn,
                                            const int* __restrict__ flag) {
  const int mode = flag[0];
  const int blk = blockIdx.x;
  const int n = blk >> 8, l = blk & 255;
  const int b = n >> 6, ih = (n >> 3) & 7, iw = n & 7;
  const int t = l >> 6, r = (l >> 3) & 7, s = l & 7;
  const int bt = b * 4 + t;
  const int h = ih * 8 + r, w = iw * 8 + s;
  const int c = threadIdx.x;
  const float val = ldin(x, (((size_t)bt * 256 + c) * 64 + h) * 64 + w, mode);

  float s1 = val, s2 = val * val;
#pragma unroll
  for (int off = 32; off > 0; off >>= 1) {
    s1 += __shfl_down(s1, off, 64);
    s2 += __shfl_down(s2, off, 64);
  }
  __shared__ float red[8];
  const int wid = threadIdx.x >> 6;
  if ((threadIdx.x & 63) == 0) { red[wid] = s1; red[4 + wid] = s2; }
  __syncthreads();
  if (threadIdx.x == 0) {
    float a = red[0] + red[1] + red[2] + red[3];
    float q = red[4] + red[5] + red[6] + red[7];
    float mu = a * (1.0f / 256.0f);
    float var = fmaxf(q * (1.0f / 256.0f) - mu * mu, 0.0f);
    red[0] = mu;
    red[1] = rsqrtf(var + EPS_F);
  }
  __syncthreads();
  const float mu = red[0], rs = red[1];
  const float o = (val - mu) * rs * ldin(gamma, c, mode) + ldin(beta, c, mode);
  xn[(size_t)blk * 256 + c] = f2b(o);
}

// ---------------------------------------------------------------------------
// Kernel 2: MFMA qkv GEMM. out[row,col] = sum_k A[row,k] * Wt[col,k] + bias.
// Block = 4 waves, 128x128 tile; wave w = (wy*2+wx) owns 64x64 subtile as
// 4x4 grid of 16x16x32 accumulators. BK=64 bf16 LDS tiles, +8 pad.
// ---------------------------------------------------------------------------
__global__ __launch_bounds__(256) void k_qkv(const bf16* __restrict__ A,
                                             const void* __restrict__ Wt,
                                             const void* __restrict__ bias,
                                             bf16* __restrict__ out,
                                             int row_base,
                                             const int* __restrict__ flag) {
  const int mode = flag[0];
  __shared__ short sA[128][72];
  __shared__ short sB[128][72];
  const int row0 = blockIdx.x * 128;   // chunk-local
  const int col0 = blockIdx.y * 128;
  const int tid = threadIdx.x;
  const int wid = tid >> 6, lane = tid & 63;
  const int wy = wid >> 1, wx = wid & 1;
  const int l15 = lane & 15, quad = lane >> 4;
  const short* Ab = (const short*)A;

  f32x4 acc[4][4];
#pragma unroll
  for (int i = 0; i < 4; ++i)
#pragma unroll
    for (int j = 0; j < 4; ++j) acc[i][j] = (f32x4){0.f, 0.f, 0.f, 0.f};

  for (int k0 = 0; k0 < 256; k0 += 64) {
    if (k0) __syncthreads();  // WAR on LDS reuse
#pragma unroll
    for (int it = 0; it < 4; ++it) {
      const int id = tid + it * 256;           // 0..1023
      const int rr = id >> 3, c8 = (id & 7) * 8;
      *(short8*)&sA[rr][c8] =
          *(const short8*)(Ab + (size_t)(row_base + row0 + rr) * 256 + k0 + c8);
      *(short8*)&sB[rr][c8] = ldin8(Wt, (size_t)(col0 + rr) * 256 + k0 + c8, mode);
    }
    __syncthreads();
#pragma unroll
    for (int kk = 0; kk < 64; kk += 32) {
      short8 af[4], bfv[4];
#pragma unroll
      for (int i = 0; i < 4; ++i)
        af[i] = *(const short8*)&sA[wy * 64 + i * 16 + l15][kk + quad * 8];
#pragma unroll
      for (int j = 0; j < 4; ++j)
        bfv[j] = *(const short8*)&sB[wx * 64 + j * 16 + l15][kk + quad * 8];
#pragma unroll
      for (int i = 0; i < 4; ++i)
#pragma unroll
        for (int j = 0; j < 4; ++j)
          acc[i][j] = __builtin_amdgcn_mfma_f32_16x16x32_bf16(af[i], bfv[j], acc[i][j], 0, 0, 0);
    }
  }

  // Epilogue: C/D row = wy*64+i*16+quad*4+r, col = wx*64+j*16+l15
#pragma unroll
  for (int j = 0; j < 4; ++j) {
    const int col = col0 + wx * 64 + j * 16 + l15;
    const float bj = ldin(bias, col, mode);
#pragma unroll
    for (int i = 0; i < 4; ++i) {
      const int row = row0 + wy * 64 + i * 16 + quad * 4;
#pragma unroll
      for (int r = 0; r < 4; ++r)
        out[(size_t)(row + r) * 768 + col] = f2b(acc[i][j][r] + bj);
    }
  }
}

// ---------------------------------------------------------------------------
// Kernel 3: MFMA attention (unchanged from R5-passing version).
// ---------------------------------------------------------------------------
__global__ __launch_bounds__(256) void k_attn(const bf16* __restrict__ qkv,
                                              bf16* __restrict__ aout,
                                              int n_base) {
  const int n_loc = blockIdx.x >> 3, hh = blockIdx.x & 7;
  const int n_glob = n_base + n_loc;
  __shared__ short sK[256][40];
  __shared__ short sVt[32][264];
  __shared__ short sP[4][16][136];
  const int tid = threadIdx.x;
  const int wid = tid >> 6, lane = tid & 63;
  const int l15 = lane & 15, quad = lane >> 4;
  const short* qg = (const short*)qkv;
  const size_t base = (size_t)n_loc * 256 * 768 + hh * 32;

  for (int c = tid; c < 1024; c += 256) {
    const int m = c >> 2, d0 = (c & 3) * 8;
    *(short8*)&sK[m][d0] = *(const short8*)(qg + base + (size_t)m * 768 + 256 + d0);
    short8 vv = *(const short8*)(qg + base + (size_t)m * 768 + 512 + d0);
#pragma unroll
    for (int j = 0; j < 8; ++j) sVt[d0 + j][m] = vv[j];
  }
  __syncthreads();

  const int R0 = wid * 64;
  const float esc = SCALE_F * LOG2E_F;

  for (int lt = 0; lt < 4; ++lt) {
    const int lrow = R0 + lt * 16;
    const short8 qf = *(const short8*)(qg + base + (size_t)(lrow + l15) * 768 + quad * 8);

    f32x4 sacc[16];
#pragma unroll
    for (int t = 0; t < 16; ++t) {
      sacc[t] = (f32x4){0.f, 0.f, 0.f, 0.f};
      const short8 kf = *(const short8*)&sK[t * 16 + l15][quad * 8];
      sacc[t] = __builtin_amdgcn_mfma_f32_16x16x32_bf16(qf, kf, sacc[t], 0, 0, 0);
    }

    float mx[4] = {-3.0e38f, -3.0e38f, -3.0e38f, -3.0e38f};
#pragma unroll
    for (int t = 0; t < 16; ++t)
#pragma unroll
      for (int r = 0; r < 4; ++r) mx[r] = fmaxf(mx[r], sacc[t][r]);
#pragma unroll
    for (int m = 1; m < 16; m <<= 1)
#pragma unroll
      for (int r = 0; r < 4; ++r) mx[r] = fmaxf(mx[r], __shfl_xor(mx[r], m, 64));
    float sum[4] = {0.f, 0.f, 0.f, 0.f};
#pragma unroll
    for (int t = 0; t < 16; ++t)
#pragma unroll
      for (int r = 0; r < 4; ++r) {
        const float p = exp2f((sacc[t][r] - mx[r]) * esc);
        sacc[t][r] = p;
        sum[r] += p;
      }
#pragma unroll
    for (int m = 1; m < 16; m <<= 1)
#pragma unroll
      for (int r = 0; r < 4; ++r) sum[r] += __shfl_xor(sum[r], m, 64);
    float inv[4];
#pragma unroll
    for (int r = 0; r < 4; ++r) inv[r] = 1.0f / sum[r];

    f32x4 oacc[2] = {(f32x4){0.f, 0.f, 0.f, 0.f}, (f32x4){0.f, 0.f, 0.f, 0.f}};
    for (int half = 0; half < 2; ++half) {
      __syncthreads();
#pragma unroll
      for (int t = 0; t < 8; ++t) {
        const int tt = half * 8 + t;
#pragma unroll
        for (int r = 0; r < 4; ++r)
          sP[wid][quad * 4 + r][t * 16 + l15] = f2bs(sacc[tt][r]);
      }
      __syncthreads();
#pragma unroll
      for (int kk = 0; kk < 4; ++kk) {
        const short8 pf = *(const short8*)&sP[wid][l15][kk * 32 + quad * 8];
#pragma unroll
        for (int dt = 0; dt < 2; ++dt) {
          const short8 vf =
              *(const short8*)&sVt[dt * 16 + l15][half * 128 + kk * 32 + quad * 8];
          oacc[dt] = __builtin_amdgcn_mfma_f32_16x16x32_bf16(pf, vf, oacc[dt], 0, 0, 0);
        }
      }
    }

#pragma unroll
    for (int dt = 0; dt < 2; ++dt)
#pragma unroll
      for (int r = 0; r < 4; ++r) {
        const int l = lrow + quad * 4 + r;
        aout[((size_t)n_glob * 256 + l) * 256 + hh * 32 + dt * 16 + l15] =
            f2b(oacc[dt][r] * inv[r]);
      }
  }
}

// ---------------------------------------------------------------------------
// Kernel 4: MFMA proj GEMM + bias + residual + scatter. Same core as k_qkv.
// ---------------------------------------------------------------------------
__global__ __launch_bounds__(256) void k_proj(const bf16* __restrict__ A,
                                              const void* __restrict__ Wp,
                                              const void* __restrict__ bias,
                                              const void* __restrict__ x,
                                              void* __restrict__ out,
                                              const int* __restrict__ flag) {
  const int mode = flag[0];
  __shared__ short sA[128][72];
  __shared__ short sB[128][72];
  const int row0 = blockIdx.x * 128;
  const int col0 = blockIdx.y * 128;
  const int tid = threadIdx.x;
  const int wid = tid >> 6, lane = tid & 63;
  const int wy = wid >> 1, wx = wid & 1;
  const int l15 = lane & 15, quad = lane >> 4;
  const short* Ab = (const short*)A;

  f32x4 acc[4][4];
#pragma unroll
  for (int i = 0; i < 4; ++i)
#pragma unroll
    for (int j = 0; j < 4; ++j) acc[i][j] = (f32x4){0.f, 0.f, 0.f, 0.f};

  for (int k0 = 0; k0 < 256; k0 += 64) {
    if (k0) __syncthreads();
#pragma unroll
    for (int it = 0; it < 4; ++it) {
      const int id = tid + it * 256;
      const int rr = id >> 3, c8 = (id & 7) * 8;
      *(short8*)&sA[rr][c8] =
          *(const short8*)(Ab + (size_t)(row0 + rr) * 256 + k0 + c8);
      *(short8*)&sB[rr][c8] = ldin8(Wp, (size_t)(col0 + rr) * 256 + k0 + c8, mode);
    }
    __syncthreads();
#pragma unroll
    for (int kk = 0; kk < 64; kk += 32) {
      short8 af[4], bfv[4];
#pragma unroll
      for (int i = 0; i < 4; ++i)
        af[i] = *(const short8*)&sA[wy * 64 + i * 16 + l15][kk + quad * 8];
#pragma unroll
      for (int j = 0; j < 4; ++j)
        bfv[j] = *(const short8*)&sB[wx * 64 + j * 16 + l15][kk + quad * 8];
#pragma unroll
      for (int i = 0; i < 4; ++i)
#pragma unroll
        for (int j = 0; j < 4; ++j)
          acc[i][j] = __builtin_amdgcn_mfma_f32_16x16x32_bf16(af[i], bfv[j], acc[i][j], 0, 0, 0);
    }
  }

  // Epilogue: bias + residual + scatter to (BT, C, H, W)
#pragma unroll
  for (int i = 0; i < 4; ++i) {
#pragma unroll
    for (int r = 0; r < 4; ++r) {
      const int row = row0 + wy * 64 + i * 16 + quad * 4 + r;  // n*256 + l
      const int n = row >> 8, l = row & 255;
      const int b = n >> 6, ih = (n >> 3) & 7, iw = n & 7;
      const int t = l >> 6, rr = (l >> 3) & 7, s = l & 7;
      const int bt = b * 4 + t;
      const int h = ih * 8 + rr, w = iw * 8 + s;
      const size_t gbase = (((size_t)bt * 256) * 64 + h) * 64 + w;
#pragma unroll
      for (int j = 0; j < 4; ++j) {
        const int c = col0 + wx * 64 + j * 16 + l15;
        const size_t gaddr = gbase + (size_t)c * 4096;
        const float o = acc[i][j][r] + ldin(bias, c, mode) + ldin(x, gaddr, mode);
        stout(out, gaddr, mode, o);
      }
    }
  }
}

// ---------------------------------------------------------------------------
extern "C" void kernel_launch(void* const* d_in, const int* in_sizes, int n_in,
                              void* d_out, int out_size, void* d_ws, size_t ws_size,
                              hipStream_t stream) {
  (void)in_sizes; (void)n_in; (void)out_size; (void)ws_size;
  const void* x      = d_in[0];
  const void* w_qkv  = d_in[1];
  const void* b_qkv  = d_in[2];
  const void* w_proj = d_in[3];
  const void* b_proj = d_in[4];
  const void* gamma  = d_in[5];
  const void* beta   = d_in[6];

  char* ws = (char*)d_ws;
  int* flag   = (int*)ws;                               // 4 B (+pad to 1 KiB)
  bf16* xnbuf = (bf16*)(ws + 1024);                     // 32768*256*2 = 16 MiB
  bf16* qkvc  = (bf16*)(ws + 1024 + (size_t)16777216);  // 8192*768*2 = 12.6 MiB

  hipLaunchKernelGGL(k_probe, dim3(1), dim3(256), 0, stream, (const float*)x, flag);
  hipLaunchKernelGGL(k_ln, dim3(32768), dim3(256), 0, stream, x, gamma, beta, xnbuf, flag);
  for (int c = 0; c < 4; ++c) {
    hipLaunchKernelGGL(k_qkv, dim3(64, 6), dim3(256), 0, stream,
                       xnbuf, w_qkv, b_qkv, qkvc, c * ROWS_CHUNK, flag);
    hipLaunchKernelGGL(k_attn, dim3(NW_CHUNK * 8), dim3(256), 0, stream,
                       qkvc, xnbuf, c * NW_CHUNK);
  }
  hipLaunchKernelGGL(k_proj, dim3(256, 2), dim3(256), 0, stream,
                     xnbuf, w_proj, b_proj, x, d_out, flag);
}

// Round 8
// 304.192 us; speedup vs baseline: 6.2655x; 1.3509x over previous
//
#include <hip/hip_runtime.h>
#include <hip/hip_bf16.h>

typedef __hip_bfloat16 bf16;
typedef __attribute__((ext_vector_type(8))) short short8;   // 8 bf16 bits (4 VGPRs)
typedef __attribute__((ext_vector_type(4))) float f32x4;    // MFMA C/D

// Problem constants: B=2, T=4, H=W=64, C=256, ws=8
// N = 128 windows, L = 256 tokens, C = 256, heads = 8, head_dim = 32
#define SCALE_F 0.17677669529663687f
#define LOG2E_F 1.4426950408889634f
#define EPS_F 1e-5f
#define NW_CHUNK 32                 // windows per pipeline chunk (4 chunks)
#define ROWS_CHUNK (NW_CHUNK * 256) // 8192 token-rows per chunk

__device__ __forceinline__ float b2f(bf16 v) { return __bfloat162float(v); }
__device__ __forceinline__ bf16 f2b(float v) { return __float2bfloat16(v); }
__device__ __forceinline__ short f2bs(float v) { bf16 h = f2b(v); return *(short*)&h; }
// R7 bug: b2f(short) implicitly converted the BIT PATTERN numerically
// (short -> float -> bf16). This reinterprets bits, as intended.
__device__ __forceinline__ float bs2f(short s) { bf16 h = *(bf16*)&s; return __bfloat162float(h); }

// Load input element i as float. mode=1: buffer is fp32. mode=0: bf16.
__device__ __forceinline__ float ldin(const void* p, size_t i, int mode) {
  if (mode) return ((const float*)p)[i];
  return b2f(((const bf16*)p)[i]);
}
__device__ __forceinline__ void stout(void* p, size_t i, int mode, float v) {
  if (mode) ((float*)p)[i] = v;
  else      ((bf16*)p)[i] = f2b(v);
}
// Load 8 consecutive elements as bf16 bit-pattern vector (weights staging).
__device__ __forceinline__ short8 ldin8(const void* p, size_t i, int mode) {
  if (mode) {
    const float* f = (const float*)p + i;
    float4 f0 = *(const float4*)f, f1 = *(const float4*)(f + 4);
    short8 r;
    r[0] = f2bs(f0.x); r[1] = f2bs(f0.y); r[2] = f2bs(f0.z); r[3] = f2bs(f0.w);
    r[4] = f2bs(f1.x); r[5] = f2bs(f1.y); r[6] = f2bs(f1.z); r[7] = f2bs(f1.w);
    return r;
  }
  return *(const short8*)((const short*)p + i);
}

// ---------------------------------------------------------------------------
// Probe: classify input dtype (1 = fp32, 0 = bf16).
// ---------------------------------------------------------------------------
__global__ __launch_bounds__(256) void k_probe(const float* __restrict__ xf,
                                               int* __restrict__ flag) {
  __shared__ int cnt;
  if (threadIdx.x == 0) cnt = 0;
  __syncthreads();
  int bad = 0;
  for (int i = threadIdx.x; i < 1024; i += 256) {
    const float v = xf[i];
    if (!(fabsf(v) < 1e20f)) bad++;
  }
  atomicAdd(&cnt, bad);
  __syncthreads();
  if (threadIdx.x == 0) flag[0] = (cnt < 8) ? 1 : 0;
}

// ---------------------------------------------------------------------------
// Kernel 1: gather + LayerNorm, blocked for coalescing. Block = (n, t):
// lanes = 8x8 spatial patch (64 tokens), loop over channels -> 32 B-contiguous
// reads. Values round-trip LDS as bf16 bits; xn written fully coalesced.
// ---------------------------------------------------------------------------
__global__ __launch_bounds__(256) void k_ln(const void* __restrict__ x,
                                            const void* __restrict__ gamma,
                                            const void* __restrict__ beta,
                                            bf16* __restrict__ xn,
                                            const int* __restrict__ flag) {
  const int mode = flag[0];
  const int n = blockIdx.x >> 2, t = blockIdx.x & 3;
  const int b = n >> 6, ih = (n >> 3) & 7, iw = n & 7;
  const int bt = b * 4 + t;
  const int tid = threadIdx.x;
  const int tok = tid & 63, cq = tid >> 6;
  const int r = tok >> 3, s = tok & 7;
  const int h = ih * 8 + r, w = iw * 8 + s;
  const size_t sbase = (size_t)bt * 1048576 + h * 64 + w;

  __shared__ short sX[256][66];       // [c][tok] bf16 bits; 66-short rows
  __shared__ float sred[4][64], sqred[4][64];
  __shared__ float smu[64], srs[64];

  float sum = 0.f, sq = 0.f;
#pragma unroll 4
  for (int k = 0; k < 64; ++k) {
    const int c = cq * 64 + k;
    const float v = ldin(x, sbase + (size_t)c * 4096, mode);
    sum += v; sq += v * v;
    sX[c][tok] = f2bs(v);
  }
  sred[cq][tok] = sum; sqred[cq][tok] = sq;
  __syncthreads();
  if (tid < 64) {
    const float a = sred[0][tid] + sred[1][tid] + sred[2][tid] + sred[3][tid];
    const float q = sqred[0][tid] + sqred[1][tid] + sqred[2][tid] + sqred[3][tid];
    const float mu = a * (1.0f / 256.0f);
    const float var = fmaxf(q * (1.0f / 256.0f) - mu * mu, 0.0f);
    smu[tid] = mu; srs[tid] = rsqrtf(var + EPS_F);
  }
  __syncthreads();

  const int c = tid;  // 0..255
  const float g = ldin(gamma, c, mode), be = ldin(beta, c, mode);
  const size_t rowbase = ((size_t)n * 256 + t * 64) * 256 + c;
#pragma unroll 4
  for (int j = 0; j < 64; ++j) {
    const float v = bs2f(sX[c][j]);   // bit-reinterpret (R7 bug fixed here)
    xn[rowbase + (size_t)j * 256] = f2b((v - smu[j]) * srs[j] * g + be);
  }
}

// ---------------------------------------------------------------------------
// Kernel 2: MFMA qkv GEMM (unchanged from R6-passing version).
// ---------------------------------------------------------------------------
__global__ __launch_bounds__(256) void k_qkv(const bf16* __restrict__ A,
                                             const void* __restrict__ Wt,
                                             const void* __restrict__ bias,
                                             bf16* __restrict__ out,
                                             int row_base,
                                             const int* __restrict__ flag) {
  const int mode = flag[0];
  __shared__ short sA[128][72];
  __shared__ short sB[128][72];
  const int row0 = blockIdx.x * 128;   // chunk-local
  const int col0 = blockIdx.y * 128;
  const int tid = threadIdx.x;
  const int wid = tid >> 6, lane = tid & 63;
  const int wy = wid >> 1, wx = wid & 1;
  const int l15 = lane & 15, quad = lane >> 4;
  const short* Ab = (const short*)A;

  f32x4 acc[4][4];
#pragma unroll
  for (int i = 0; i < 4; ++i)
#pragma unroll
    for (int j = 0; j < 4; ++j) acc[i][j] = (f32x4){0.f, 0.f, 0.f, 0.f};

  for (int k0 = 0; k0 < 256; k0 += 64) {
    if (k0) __syncthreads();
#pragma unroll
    for (int it = 0; it < 4; ++it) {
      const int id = tid + it * 256;
      const int rr = id >> 3, c8 = (id & 7) * 8;
      *(short8*)&sA[rr][c8] =
          *(const short8*)(Ab + (size_t)(row_base + row0 + rr) * 256 + k0 + c8);
      *(short8*)&sB[rr][c8] = ldin8(Wt, (size_t)(col0 + rr) * 256 + k0 + c8, mode);
    }
    __syncthreads();
#pragma unroll
    for (int kk = 0; kk < 64; kk += 32) {
      short8 af[4], bfv[4];
#pragma unroll
      for (int i = 0; i < 4; ++i)
        af[i] = *(const short8*)&sA[wy * 64 + i * 16 + l15][kk + quad * 8];
#pragma unroll
      for (int j = 0; j < 4; ++j)
        bfv[j] = *(const short8*)&sB[wx * 64 + j * 16 + l15][kk + quad * 8];
#pragma unroll
      for (int i = 0; i < 4; ++i)
#pragma unroll
        for (int j = 0; j < 4; ++j)
          acc[i][j] = __builtin_amdgcn_mfma_f32_16x16x32_bf16(af[i], bfv[j], acc[i][j], 0, 0, 0);
    }
  }

#pragma unroll
  for (int j = 0; j < 4; ++j) {
    const int col = col0 + wx * 64 + j * 16 + l15;
    const float bj = ldin(bias, col, mode);
#pragma unroll
    for (int i = 0; i < 4; ++i) {
      const int row = row0 + wy * 64 + i * 16 + quad * 4;
#pragma unroll
      for (int r = 0; r < 4; ++r)
        out[(size_t)(row + r) * 768 + col] = f2b(acc[i][j][r] + bj);
    }
  }
}

// ---------------------------------------------------------------------------
// Kernel 3: MFMA attention (unchanged from R5-passing version).
// ---------------------------------------------------------------------------
__global__ __launch_bounds__(256) void k_attn(const bf16* __restrict__ qkv,
                                              bf16* __restrict__ aout,
                                              int n_base) {
  const int n_loc = blockIdx.x >> 3, hh = blockIdx.x & 7;
  const int n_glob = n_base + n_loc;
  __shared__ short sK[256][40];
  __shared__ short sVt[32][264];
  __shared__ short sP[4][16][136];
  const int tid = threadIdx.x;
  const int wid = tid >> 6, lane = tid & 63;
  const int l15 = lane & 15, quad = lane >> 4;
  const short* qg = (const short*)qkv;
  const size_t base = (size_t)n_loc * 256 * 768 + hh * 32;

  for (int c = tid; c < 1024; c += 256) {
    const int m = c >> 2, d0 = (c & 3) * 8;
    *(short8*)&sK[m][d0] = *(const short8*)(qg + base + (size_t)m * 768 + 256 + d0);
    short8 vv = *(const short8*)(qg + base + (size_t)m * 768 + 512 + d0);
#pragma unroll
    for (int j = 0; j < 8; ++j) sVt[d0 + j][m] = vv[j];
  }
  __syncthreads();

  const int R0 = wid * 64;
  const float esc = SCALE_F * LOG2E_F;

  for (int lt = 0; lt < 4; ++lt) {
    const int lrow = R0 + lt * 16;
    const short8 qf = *(const short8*)(qg + base + (size_t)(lrow + l15) * 768 + quad * 8);

    f32x4 sacc[16];
#pragma unroll
    for (int t = 0; t < 16; ++t) {
      sacc[t] = (f32x4){0.f, 0.f, 0.f, 0.f};
      const short8 kf = *(const short8*)&sK[t * 16 + l15][quad * 8];
      sacc[t] = __builtin_amdgcn_mfma_f32_16x16x32_bf16(qf, kf, sacc[t], 0, 0, 0);
    }

    float mx[4] = {-3.0e38f, -3.0e38f, -3.0e38f, -3.0e38f};
#pragma unroll
    for (int t = 0; t < 16; ++t)
#pragma unroll
      for (int r = 0; r < 4; ++r) mx[r] = fmaxf(mx[r], sacc[t][r]);
#pragma unroll
    for (int m = 1; m < 16; m <<= 1)
#pragma unroll
      for (int r = 0; r < 4; ++r) mx[r] = fmaxf(mx[r], __shfl_xor(mx[r], m, 64));
    float sum[4] = {0.f, 0.f, 0.f, 0.f};
#pragma unroll
    for (int t = 0; t < 16; ++t)
#pragma unroll
      for (int r = 0; r < 4; ++r) {
        const float p = exp2f((sacc[t][r] - mx[r]) * esc);
        sacc[t][r] = p;
        sum[r] += p;
      }
#pragma unroll
    for (int m = 1; m < 16; m <<= 1)
#pragma unroll
      for (int r = 0; r < 4; ++r) sum[r] += __shfl_xor(sum[r], m, 64);
    float inv[4];
#pragma unroll
    for (int r = 0; r < 4; ++r) inv[r] = 1.0f / sum[r];

    f32x4 oacc[2] = {(f32x4){0.f, 0.f, 0.f, 0.f}, (f32x4){0.f, 0.f, 0.f, 0.f}};
    for (int half = 0; half < 2; ++half) {
      __syncthreads();
#pragma unroll
      for (int t = 0; t < 8; ++t) {
        const int tt = half * 8 + t;
#pragma unroll
        for (int r = 0; r < 4; ++r)
          sP[wid][quad * 4 + r][t * 16 + l15] = f2bs(sacc[tt][r]);
      }
      __syncthreads();
#pragma unroll
      for (int kk = 0; kk < 4; ++kk) {
        const short8 pf = *(const short8*)&sP[wid][l15][kk * 32 + quad * 8];
#pragma unroll
        for (int dt = 0; dt < 2; ++dt) {
          const short8 vf =
              *(const short8*)&sVt[dt * 16 + l15][half * 128 + kk * 32 + quad * 8];
          oacc[dt] = __builtin_amdgcn_mfma_f32_16x16x32_bf16(pf, vf, oacc[dt], 0, 0, 0);
        }
      }
    }

#pragma unroll
    for (int dt = 0; dt < 2; ++dt)
#pragma unroll
      for (int r = 0; r < 4; ++r) {
        const int l = lrow + quad * 4 + r;
        aout[((size_t)n_glob * 256 + l) * 256 + hh * 32 + dt * 16 + l15] =
            f2b(oacc[dt][r] * inv[r]);
      }
  }
}

// ---------------------------------------------------------------------------
// Kernel 4: MFMA proj GEMM + bias + residual + scatter. Epilogue transposes
// each 16x16 C-tile through a per-wave LDS slab so lanes hold consecutive
// TOKENS for a fixed channel -> residual read + out write become 32 B
// contiguous segments instead of 4 B scatter.
// ---------------------------------------------------------------------------
__global__ __launch_bounds__(256) void k_proj(const bf16* __restrict__ A,
                                              const void* __restrict__ Wp,
                                              const void* __restrict__ bias,
                                              const void* __restrict__ x,
                                              void* __restrict__ out,
                                              const int* __restrict__ flag) {
  const int mode = flag[0];
  __shared__ short sA[128][72];
  __shared__ short sB[128][72];
  __shared__ float sT[4][16][17];     // per-wave transpose slab
  const int row0 = blockIdx.x * 128;
  const int col0 = blockIdx.y * 128;
  const int tid = threadIdx.x;
  const int wid = tid >> 6, lane = tid & 63;
  const int wy = wid >> 1, wx = wid & 1;
  const int l15 = lane & 15, quad = lane >> 4;
  const short* Ab = (const short*)A;

  f32x4 acc[4][4];
#pragma unroll
  for (int i = 0; i < 4; ++i)
#pragma unroll
    for (int j = 0; j < 4; ++j) acc[i][j] = (f32x4){0.f, 0.f, 0.f, 0.f};

  for (int k0 = 0; k0 < 256; k0 += 64) {
    if (k0) __syncthreads();
#pragma unroll
    for (int it = 0; it < 4; ++it) {
      const int id = tid + it * 256;
      const int rr = id >> 3, c8 = (id & 7) * 8;
      *(short8*)&sA[rr][c8] =
          *(const short8*)(Ab + (size_t)(row0 + rr) * 256 + k0 + c8);
      *(short8*)&sB[rr][c8] = ldin8(Wp, (size_t)(col0 + rr) * 256 + k0 + c8, mode);
    }
    __syncthreads();
#pragma unroll
    for (int kk = 0; kk < 64; kk += 32) {
      short8 af[4], bfv[4];
#pragma unroll
      for (int i = 0; i < 4; ++i)
        af[i] = *(const short8*)&sA[wy * 64 + i * 16 + l15][kk + quad * 8];
#pragma unroll
      for (int j = 0; j < 4; ++j)
        bfv[j] = *(const short8*)&sB[wx * 64 + j * 16 + l15][kk + quad * 8];
#pragma unroll
      for (int i = 0; i < 4; ++i)
#pragma unroll
        for (int j = 0; j < 4; ++j)
          acc[i][j] = __builtin_amdgcn_mfma_f32_16x16x32_bf16(af[i], bfv[j], acc[i][j], 0, 0, 0);
    }
  }

  // Transposed epilogue. Per-wave slab: DS ops from one wave drain with
  // lgkmcnt(0); no block barrier needed.
#pragma unroll
  for (int i = 0; i < 4; ++i) {
#pragma unroll
    for (int j = 0; j < 4; ++j) {
#pragma unroll
      for (int r = 0; r < 4; ++r)
        sT[wid][quad * 4 + r][l15] = acc[i][j][r];   // [token][channel]
      asm volatile("s_waitcnt lgkmcnt(0)" ::: "memory");
#pragma unroll
      for (int r2 = 0; r2 < 4; ++r2) {
        const float v = sT[wid][l15][quad * 4 + r2]; // lane: tok=l15, ch=4q+r2
        const int row = row0 + wy * 64 + i * 16 + l15;       // n*256 + l
        const int c   = col0 + wx * 64 + j * 16 + quad * 4 + r2;
        const int n = row >> 8, l = row & 255;
        const int b = n >> 6, ih = (n >> 3) & 7, iw = n & 7;
        const int tt = l >> 6, rr = (l >> 3) & 7, ss = l & 7;
        const int bt = b * 4 + tt;
        const size_t gaddr = (size_t)bt * 1048576 + (size_t)c * 4096 +
                             (ih * 8 + rr) * 64 + iw * 8 + ss;
        const float o = v + ldin(bias, c, mode) + ldin(x, gaddr, mode);
        stout(out, gaddr, mode, o);
      }
      asm volatile("s_waitcnt lgkmcnt(0)" ::: "memory");  // WAR before reuse
    }
  }
}

// ---------------------------------------------------------------------------
extern "C" void kernel_launch(void* const* d_in, const int* in_sizes, int n_in,
                              void* d_out, int out_size, void* d_ws, size_t ws_size,
                              hipStream_t stream) {
  (void)in_sizes; (void)n_in; (void)out_size; (void)ws_size;
  const void* x      = d_in[0];
  const void* w_qkv  = d_in[1];
  const void* b_qkv  = d_in[2];
  const void* w_proj = d_in[3];
  const void* b_proj = d_in[4];
  const void* gamma  = d_in[5];
  const void* beta   = d_in[6];

  char* ws = (char*)d_ws;
  int* flag   = (int*)ws;                               // 4 B (+pad to 1 KiB)
  bf16* xnbuf = (bf16*)(ws + 1024);                     // 32768*256*2 = 16 MiB
  bf16* qkvc  = (bf16*)(ws + 1024 + (size_t)16777216);  // 8192*768*2 = 12.6 MiB

  hipLaunchKernelGGL(k_probe, dim3(1), dim3(256), 0, stream, (const float*)x, flag);
  hipLaunchKernelGGL(k_ln, dim3(512), dim3(256), 0, stream, x, gamma, beta, xnbuf, flag);
  for (int c = 0; c < 4; ++c) {
    hipLaunchKernelGGL(k_qkv, dim3(64, 6), dim3(256), 0, stream,
                       xnbuf, w_qkv, b_qkv, qkvc, c * ROWS_CHUNK, flag);
    hipLaunchKernelGGL(k_attn, dim3(NW_CHUNK * 8), dim3(256), 0, stream,
                       qkvc, xnbuf, c * NW_CHUNK);
  }
  hipLaunchKernelGGL(k_proj, dim3(256, 2), dim3(256), 0, stream,
                     xnbuf, w_proj, b_proj, x, d_out, flag);
}

// Round 9
// 261.639 us; speedup vs baseline: 7.2845x; 1.1626x over previous
//
#include <hip/hip_runtime.h>
#include <hip/hip_bf16.h>

typedef __hip_bfloat16 bf16;
typedef __attribute__((ext_vector_type(8))) short short8;   // 8 bf16 bits (4 VGPRs)
typedef __attribute__((ext_vector_type(4))) float f32x4;    // MFMA C/D

// Problem constants: B=2, T=4, H=W=64, C=256, ws=8
// N = 128 windows, L = 256 tokens, C = 256, heads = 8, head_dim = 32
#define SCALE_F 0.17677669529663687f
#define LOG2E_F 1.4426950408889634f
#define EPS_F 1e-5f
#define NW_CHUNK 32                 // windows per chunk (fallback path)
#define ROWS_CHUNK (NW_CHUNK * 256)

__device__ __forceinline__ float b2f(bf16 v) { return __bfloat162float(v); }
__device__ __forceinline__ bf16 f2b(float v) { return __float2bfloat16(v); }
__device__ __forceinline__ short f2bs(float v) { bf16 h = f2b(v); return *(short*)&h; }
__device__ __forceinline__ float bs2f(short s) { bf16 h = *(bf16*)&s; return __bfloat162float(h); }

__device__ __forceinline__ float ldin(const void* p, size_t i, int mode) {
  if (mode) return ((const float*)p)[i];
  return b2f(((const bf16*)p)[i]);
}
__device__ __forceinline__ void stout(void* p, size_t i, int mode, float v) {
  if (mode) ((float*)p)[i] = v;
  else      ((bf16*)p)[i] = f2b(v);
}
__device__ __forceinline__ short8 ldin8(const void* p, size_t i, int mode) {
  if (mode) {
    const float* f = (const float*)p + i;
    float4 f0 = *(const float4*)f, f1 = *(const float4*)(f + 4);
    short8 r;
    r[0] = f2bs(f0.x); r[1] = f2bs(f0.y); r[2] = f2bs(f0.z); r[3] = f2bs(f0.w);
    r[4] = f2bs(f1.x); r[5] = f2bs(f1.y); r[6] = f2bs(f1.z); r[7] = f2bs(f1.w);
    return r;
  }
  return *(const short8*)((const short*)p + i);
}

// ---------------------------------------------------------------------------
// Probe: classify input dtype (1 = fp32, 0 = bf16).
// ---------------------------------------------------------------------------
__global__ __launch_bounds__(256) void k_probe(const float* __restrict__ xf,
                                               int* __restrict__ flag) {
  __shared__ int cnt;
  if (threadIdx.x == 0) cnt = 0;
  __syncthreads();
  int bad = 0;
  for (int i = threadIdx.x; i < 1024; i += 256) {
    const float v = xf[i];
    if (!(fabsf(v) < 1e20f)) bad++;
  }
  atomicAdd(&cnt, bad);
  __syncthreads();
  if (threadIdx.x == 0) flag[0] = (cnt < 8) ? 1 : 0;
}

// ---------------------------------------------------------------------------
// Kernel 1: gather + LayerNorm (R8-passing version, unchanged).
// ---------------------------------------------------------------------------
__global__ __launch_bounds__(256) void k_ln(const void* __restrict__ x,
                                            const void* __restrict__ gamma,
                                            const void* __restrict__ beta,
                                            bf16* __restrict__ xn,
                                            const int* __restrict__ flag) {
  const int mode = flag[0];
  const int n = blockIdx.x >> 2, t = blockIdx.x & 3;
  const int b = n >> 6, ih = (n >> 3) & 7, iw = n & 7;
  const int bt = b * 4 + t;
  const int tid = threadIdx.x;
  const int tok = tid & 63, cq = tid >> 6;
  const int r = tok >> 3, s = tok & 7;
  const int h = ih * 8 + r, w = iw * 8 + s;
  const size_t sbase = (size_t)bt * 1048576 + h * 64 + w;

  __shared__ short sX[256][66];
  __shared__ float sred[4][64], sqred[4][64];
  __shared__ float smu[64], srs[64];

  float sum = 0.f, sq = 0.f;
#pragma unroll 4
  for (int k = 0; k < 64; ++k) {
    const int c = cq * 64 + k;
    const float v = ldin(x, sbase + (size_t)c * 4096, mode);
    sum += v; sq += v * v;
    sX[c][tok] = f2bs(v);
  }
  sred[cq][tok] = sum; sqred[cq][tok] = sq;
  __syncthreads();
  if (tid < 64) {
    const float a = sred[0][tid] + sred[1][tid] + sred[2][tid] + sred[3][tid];
    const float q = sqred[0][tid] + sqred[1][tid] + sqred[2][tid] + sqred[3][tid];
    const float mu = a * (1.0f / 256.0f);
    const float var = fmaxf(q * (1.0f / 256.0f) - mu * mu, 0.0f);
    smu[tid] = mu; srs[tid] = rsqrtf(var + EPS_F);
  }
  __syncthreads();

  const int c = tid;
  const float g = ldin(gamma, c, mode), be = ldin(beta, c, mode);
  const size_t rowbase = ((size_t)n * 256 + t * 64) * 256 + c;
#pragma unroll 4
  for (int j = 0; j < 64; ++j) {
    const float v = bs2f(sX[c][j]);
    xn[rowbase + (size_t)j * 256] = f2b((v - smu[j]) * srs[j] * g + be);
  }
}

// ---------------------------------------------------------------------------
// Kernel 2: MFMA qkv GEMM (R6-passing core; row_base selects chunk or 0).
// ---------------------------------------------------------------------------
__global__ __launch_bounds__(256) void k_qkv(const bf16* __restrict__ A,
                                             const void* __restrict__ Wt,
                                             const void* __restrict__ bias,
                                             bf16* __restrict__ out,
                                             int row_base,
                                             const int* __restrict__ flag) {
  const int mode = flag[0];
  __shared__ short sA[128][72];
  __shared__ short sB[128][72];
  const int row0 = blockIdx.x * 128;
  const int col0 = blockIdx.y * 128;
  const int tid = threadIdx.x;
  const int wid = tid >> 6, lane = tid & 63;
  const int wy = wid >> 1, wx = wid & 1;
  const int l15 = lane & 15, quad = lane >> 4;
  const short* Ab = (const short*)A;

  f32x4 acc[4][4];
#pragma unroll
  for (int i = 0; i < 4; ++i)
#pragma unroll
    for (int j = 0; j < 4; ++j) acc[i][j] = (f32x4){0.f, 0.f, 0.f, 0.f};

  for (int k0 = 0; k0 < 256; k0 += 64) {
    if (k0) __syncthreads();
#pragma unroll
    for (int it = 0; it < 4; ++it) {
      const int id = tid + it * 256;
      const int rr = id >> 3, c8 = (id & 7) * 8;
      *(short8*)&sA[rr][c8] =
          *(const short8*)(Ab + (size_t)(row_base + row0 + rr) * 256 + k0 + c8);
      *(short8*)&sB[rr][c8] = ldin8(Wt, (size_t)(col0 + rr) * 256 + k0 + c8, mode);
    }
    __syncthreads();
#pragma unroll
    for (int kk = 0; kk < 64; kk += 32) {
      short8 af[4], bfv[4];
#pragma unroll
      for (int i = 0; i < 4; ++i)
        af[i] = *(const short8*)&sA[wy * 64 + i * 16 + l15][kk + quad * 8];
#pragma unroll
      for (int j = 0; j < 4; ++j)
        bfv[j] = *(const short8*)&sB[wx * 64 + j * 16 + l15][kk + quad * 8];
#pragma unroll
      for (int i = 0; i < 4; ++i)
#pragma unroll
        for (int j = 0; j < 4; ++j)
          acc[i][j] = __builtin_amdgcn_mfma_f32_16x16x32_bf16(af[i], bfv[j], acc[i][j], 0, 0, 0);
    }
  }

#pragma unroll
  for (int j = 0; j < 4; ++j) {
    const int col = col0 + wx * 64 + j * 16 + l15;
    const float bj = ldin(bias, col, mode);
#pragma unroll
    for (int i = 0; i < 4; ++i) {
      const int row = row0 + wy * 64 + i * 16 + quad * 4;
#pragma unroll
      for (int r = 0; r < 4; ++r)
        out[(size_t)(row + r) * 768 + col] = f2b(acc[i][j][r] + bj);
    }
  }
}

// ---------------------------------------------------------------------------
// Kernel 3: MFMA attention. PV P-slab is PER-WAVE: block barriers replaced
// with in-wave DS ordering + s_waitcnt lgkmcnt(0) (pattern proven in k_proj
// R8 epilogue). Only the K/V staging barrier remains block-wide.
// ---------------------------------------------------------------------------
__global__ __launch_bounds__(256) void k_attn(const bf16* __restrict__ qkv,
                                              bf16* __restrict__ aout,
                                              int n_base) {
  const int n_loc = blockIdx.x >> 3, hh = blockIdx.x & 7;
  const int n_glob = n_base + n_loc;
  __shared__ short sK[256][40];
  __shared__ short sVt[32][264];
  __shared__ short sP[4][16][136];
  const int tid = threadIdx.x;
  const int wid = tid >> 6, lane = tid & 63;
  const int l15 = lane & 15, quad = lane >> 4;
  const short* qg = (const short*)qkv;
  const size_t base = (size_t)n_loc * 256 * 768 + hh * 32;

  for (int c = tid; c < 1024; c += 256) {
    const int m = c >> 2, d0 = (c & 3) * 8;
    *(short8*)&sK[m][d0] = *(const short8*)(qg + base + (size_t)m * 768 + 256 + d0);
    short8 vv = *(const short8*)(qg + base + (size_t)m * 768 + 512 + d0);
#pragma unroll
    for (int j = 0; j < 8; ++j) sVt[d0 + j][m] = vv[j];
  }
  __syncthreads();

  const int R0 = wid * 64;
  const float esc = SCALE_F * LOG2E_F;

  for (int lt = 0; lt < 4; ++lt) {
    const int lrow = R0 + lt * 16;
    const short8 qf = *(const short8*)(qg + base + (size_t)(lrow + l15) * 768 + quad * 8);

    f32x4 sacc[16];
#pragma unroll
    for (int t = 0; t < 16; ++t) {
      sacc[t] = (f32x4){0.f, 0.f, 0.f, 0.f};
      const short8 kf = *(const short8*)&sK[t * 16 + l15][quad * 8];
      sacc[t] = __builtin_amdgcn_mfma_f32_16x16x32_bf16(qf, kf, sacc[t], 0, 0, 0);
    }

    float mx[4] = {-3.0e38f, -3.0e38f, -3.0e38f, -3.0e38f};
#pragma unroll
    for (int t = 0; t < 16; ++t)
#pragma unroll
      for (int r = 0; r < 4; ++r) mx[r] = fmaxf(mx[r], sacc[t][r]);
#pragma unroll
    for (int m = 1; m < 16; m <<= 1)
#pragma unroll
      for (int r = 0; r < 4; ++r) mx[r] = fmaxf(mx[r], __shfl_xor(mx[r], m, 64));
    float sum[4] = {0.f, 0.f, 0.f, 0.f};
#pragma unroll
    for (int t = 0; t < 16; ++t)
#pragma unroll
      for (int r = 0; r < 4; ++r) {
        const float p = exp2f((sacc[t][r] - mx[r]) * esc);
        sacc[t][r] = p;
        sum[r] += p;
      }
#pragma unroll
    for (int m = 1; m < 16; m <<= 1)
#pragma unroll
      for (int r = 0; r < 4; ++r) sum[r] += __shfl_xor(sum[r], m, 64);
    float inv[4];
#pragma unroll
    for (int r = 0; r < 4; ++r) inv[r] = 1.0f / sum[r];

    f32x4 oacc[2] = {(f32x4){0.f, 0.f, 0.f, 0.f}, (f32x4){0.f, 0.f, 0.f, 0.f}};
    for (int half = 0; half < 2; ++half) {
#pragma unroll
      for (int t = 0; t < 8; ++t) {
        const int tt = half * 8 + t;
#pragma unroll
        for (int r = 0; r < 4; ++r)
          sP[wid][quad * 4 + r][t * 16 + l15] = f2bs(sacc[tt][r]);
      }
      asm volatile("s_waitcnt lgkmcnt(0)" ::: "memory");  // writes visible (wave)
#pragma unroll
      for (int kk = 0; kk < 4; ++kk) {
        const short8 pf = *(const short8*)&sP[wid][l15][kk * 32 + quad * 8];
#pragma unroll
        for (int dt = 0; dt < 2; ++dt) {
          const short8 vf =
              *(const short8*)&sVt[dt * 16 + l15][half * 128 + kk * 32 + quad * 8];
          oacc[dt] = __builtin_amdgcn_mfma_f32_16x16x32_bf16(pf, vf, oacc[dt], 0, 0, 0);
        }
      }
      asm volatile("s_waitcnt lgkmcnt(0)" ::: "memory");  // WAR before reuse
    }

#pragma unroll
    for (int dt = 0; dt < 2; ++dt)
#pragma unroll
      for (int r = 0; r < 4; ++r) {
        const int l = lrow + quad * 4 + r;
        aout[((size_t)n_glob * 256 + l) * 256 + hh * 32 + dt * 16 + l15] =
            f2b(oacc[dt][r] * inv[r]);
      }
  }
}

// ---------------------------------------------------------------------------
// Kernel 4: MFMA proj GEMM + transposed epilogue (R8-passing, unchanged).
// ---------------------------------------------------------------------------
__global__ __launch_bounds__(256) void k_proj(const bf16* __restrict__ A,
                                              const void* __restrict__ Wp,
                                              const void* __restrict__ bias,
                                              const void* __restrict__ x,
                                              void* __restrict__ out,
                                              const int* __restrict__ flag) {
  const int mode = flag[0];
  __shared__ short sA[128][72];
  __shared__ short sB[128][72];
  __shared__ float sT[4][16][17];
  const int row0 = blockIdx.x * 128;
  const int col0 = blockIdx.y * 128;
  const int tid = threadIdx.x;
  const int wid = tid >> 6, lane = tid & 63;
  const int wy = wid >> 1, wx = wid & 1;
  const int l15 = lane & 15, quad = lane >> 4;
  const short* Ab = (const short*)A;

  f32x4 acc[4][4];
#pragma unroll
  for (int i = 0; i < 4; ++i)
#pragma unroll
    for (int j = 0; j < 4; ++j) acc[i][j] = (f32x4){0.f, 0.f, 0.f, 0.f};

  for (int k0 = 0; k0 < 256; k0 += 64) {
    if (k0) __syncthreads();
#pragma unroll
    for (int it = 0; it < 4; ++it) {
      const int id = tid + it * 256;
      const int rr = id >> 3, c8 = (id & 7) * 8;
      *(short8*)&sA[rr][c8] =
          *(const short8*)(Ab + (size_t)(row0 + rr) * 256 + k0 + c8);
      *(short8*)&sB[rr][c8] = ldin8(Wp, (size_t)(col0 + rr) * 256 + k0 + c8, mode);
    }
    __syncthreads();
#pragma unroll
    for (int kk = 0; kk < 64; kk += 32) {
      short8 af[4], bfv[4];
#pragma unroll
      for (int i = 0; i < 4; ++i)
        af[i] = *(const short8*)&sA[wy * 64 + i * 16 + l15][kk + quad * 8];
#pragma unroll
      for (int j = 0; j < 4; ++j)
        bfv[j] = *(const short8*)&sB[wx * 64 + j * 16 + l15][kk + quad * 8];
#pragma unroll
      for (int i = 0; i < 4; ++i)
#pragma unroll
        for (int j = 0; j < 4; ++j)
          acc[i][j] = __builtin_amdgcn_mfma_f32_16x16x32_bf16(af[i], bfv[j], acc[i][j], 0, 0, 0);
    }
  }

#pragma unroll
  for (int i = 0; i < 4; ++i) {
#pragma unroll
    for (int j = 0; j < 4; ++j) {
#pragma unroll
      for (int r = 0; r < 4; ++r)
        sT[wid][quad * 4 + r][l15] = acc[i][j][r];
      asm volatile("s_waitcnt lgkmcnt(0)" ::: "memory");
#pragma unroll
      for (int r2 = 0; r2 < 4; ++r2) {
        const float v = sT[wid][l15][quad * 4 + r2];
        const int row = row0 + wy * 64 + i * 16 + l15;
        const int c   = col0 + wx * 64 + j * 16 + quad * 4 + r2;
        const int n = row >> 8, l = row & 255;
        const int b = n >> 6, ih = (n >> 3) & 7, iw = n & 7;
        const int tt = l >> 6, rr = (l >> 3) & 7, ss = l & 7;
        const int bt = b * 4 + tt;
        const size_t gaddr = (size_t)bt * 1048576 + (size_t)c * 4096 +
                             (ih * 8 + rr) * 64 + iw * 8 + ss;
        const float o = v + ldin(bias, c, mode) + ldin(x, gaddr, mode);
        stout(out, gaddr, mode, o);
      }
      asm volatile("s_waitcnt lgkmcnt(0)" ::: "memory");
    }
  }
}

// ---------------------------------------------------------------------------
extern "C" void kernel_launch(void* const* d_in, const int* in_sizes, int n_in,
                              void* d_out, int out_size, void* d_ws, size_t ws_size,
                              hipStream_t stream) {
  (void)in_sizes; (void)n_in; (void)out_size;
  const void* x      = d_in[0];
  const void* w_qkv  = d_in[1];
  const void* b_qkv  = d_in[2];
  const void* w_proj = d_in[3];
  const void* b_proj = d_in[4];
  const void* gamma  = d_in[5];
  const void* beta   = d_in[6];

  char* ws = (char*)d_ws;
  int* flag   = (int*)ws;                               // 4 B (+pad to 1 KiB)
  bf16* xnbuf = (bf16*)(ws + 1024);                     // 32768*256*2 = 16 MiB
  bf16* qkvb  = (bf16*)(ws + 1024 + (size_t)16777216);  // full: 48 MiB / chunk: 12.6 MiB

  const size_t need_full = 1024 + (size_t)16777216 + (size_t)32768 * 768 * 2;

  hipLaunchKernelGGL(k_probe, dim3(1), dim3(256), 0, stream, (const float*)x, flag);
  hipLaunchKernelGGL(k_ln, dim3(512), dim3(256), 0, stream, x, gamma, beta, xnbuf, flag);

  if (ws_size >= need_full) {
    // Unchunked: 5 dispatches total. qkv fully consumed before attn
    // overwrites xnbuf rows (dead-storage reuse preserved).
    hipLaunchKernelGGL(k_qkv, dim3(256, 6), dim3(256), 0, stream,
                       xnbuf, w_qkv, b_qkv, qkvb, 0, flag);
    hipLaunchKernelGGL(k_attn, dim3(1024), dim3(256), 0, stream,
                       qkvb, xnbuf, 0);
  } else {
    // Fallback: R8-proven chunked pipeline (peak ws 28.6 MiB).
    for (int c = 0; c < 4; ++c) {
      hipLaunchKernelGGL(k_qkv, dim3(64, 6), dim3(256), 0, stream,
                         xnbuf, w_qkv, b_qkv, qkvb, c * ROWS_CHUNK, flag);
      hipLaunchKernelGGL(k_attn, dim3(NW_CHUNK * 8), dim3(256), 0, stream,
                         qkvb, xnbuf, c * NW_CHUNK);
    }
  }
  hipLaunchKernelGGL(k_proj, dim3(256, 2), dim3(256), 0, stream,
                     xnbuf, w_proj, b_proj, x, d_out, flag);
}

// Round 10
// 256.641 us; speedup vs baseline: 7.4264x; 1.0195x over previous
//
#include <hip/hip_runtime.h>
#include <hip/hip_bf16.h>

typedef __hip_bfloat16 bf16;
typedef __attribute__((ext_vector_type(8))) short short8;   // 8 bf16 bits (4 VGPRs)
typedef __attribute__((ext_vector_type(4))) float f32x4;    // MFMA C/D

// Problem constants: B=2, T=4, H=W=64, C=256, ws=8
// N = 128 windows, L = 256 tokens, C = 256, heads = 8, head_dim = 32
#define SCALE_F 0.17677669529663687f
#define LOG2E_F 1.4426950408889634f
#define EPS_F 1e-5f
#define NW_CHUNK 32                 // windows per chunk (fallback path)
#define ROWS_CHUNK (NW_CHUNK * 256)

__device__ __forceinline__ float b2f(bf16 v) { return __bfloat162float(v); }
__device__ __forceinline__ bf16 f2b(float v) { return __float2bfloat16(v); }
__device__ __forceinline__ short f2bs(float v) { bf16 h = f2b(v); return *(short*)&h; }
__device__ __forceinline__ float bs2f(short s) { bf16 h = *(bf16*)&s; return __bfloat162float(h); }

__device__ __forceinline__ float ldin(const void* p, size_t i, int mode) {
  if (mode) return ((const float*)p)[i];
  return b2f(((const bf16*)p)[i]);
}
__device__ __forceinline__ void stout(void* p, size_t i, int mode, float v) {
  if (mode) ((float*)p)[i] = v;
  else      ((bf16*)p)[i] = f2b(v);
}
__device__ __forceinline__ short8 ldin8(const void* p, size_t i, int mode) {
  if (mode) {
    const float* f = (const float*)p + i;
    float4 f0 = *(const float4*)f, f1 = *(const float4*)(f + 4);
    short8 r;
    r[0] = f2bs(f0.x); r[1] = f2bs(f0.y); r[2] = f2bs(f0.z); r[3] = f2bs(f0.w);
    r[4] = f2bs(f1.x); r[5] = f2bs(f1.y); r[6] = f2bs(f1.z); r[7] = f2bs(f1.w);
    return r;
  }
  return *(const short8*)((const short*)p + i);
}

// ---------------------------------------------------------------------------
// Probe: classify input dtype (1 = fp32, 0 = bf16).
// ---------------------------------------------------------------------------
__global__ __launch_bounds__(256) void k_probe(const float* __restrict__ xf,
                                               int* __restrict__ flag) {
  __shared__ int cnt;
  if (threadIdx.x == 0) cnt = 0;
  __syncthreads();
  int bad = 0;
  for (int i = threadIdx.x; i < 1024; i += 256) {
    const float v = xf[i];
    if (!(fabsf(v) < 1e20f)) bad++;
  }
  atomicAdd(&cnt, bad);
  __syncthreads();
  if (threadIdx.x == 0) flag[0] = (cnt < 8) ? 1 : 0;
}

// ---------------------------------------------------------------------------
// Kernel 1: gather + LayerNorm (R8-passing version, unchanged).
// ---------------------------------------------------------------------------
__global__ __launch_bounds__(256) void k_ln(const void* __restrict__ x,
                                            const void* __restrict__ gamma,
                                            const void* __restrict__ beta,
                                            bf16* __restrict__ xn,
                                            const int* __restrict__ flag) {
  const int mode = flag[0];
  const int n = blockIdx.x >> 2, t = blockIdx.x & 3;
  const int b = n >> 6, ih = (n >> 3) & 7, iw = n & 7;
  const int bt = b * 4 + t;
  const int tid = threadIdx.x;
  const int tok = tid & 63, cq = tid >> 6;
  const int r = tok >> 3, s = tok & 7;
  const int h = ih * 8 + r, w = iw * 8 + s;
  const size_t sbase = (size_t)bt * 1048576 + h * 64 + w;

  __shared__ short sX[256][66];
  __shared__ float sred[4][64], sqred[4][64];
  __shared__ float smu[64], srs[64];

  float sum = 0.f, sq = 0.f;
#pragma unroll 4
  for (int k = 0; k < 64; ++k) {
    const int c = cq * 64 + k;
    const float v = ldin(x, sbase + (size_t)c * 4096, mode);
    sum += v; sq += v * v;
    sX[c][tok] = f2bs(v);
  }
  sred[cq][tok] = sum; sqred[cq][tok] = sq;
  __syncthreads();
  if (tid < 64) {
    const float a = sred[0][tid] + sred[1][tid] + sred[2][tid] + sred[3][tid];
    const float q = sqred[0][tid] + sqred[1][tid] + sqred[2][tid] + sqred[3][tid];
    const float mu = a * (1.0f / 256.0f);
    const float var = fmaxf(q * (1.0f / 256.0f) - mu * mu, 0.0f);
    smu[tid] = mu; srs[tid] = rsqrtf(var + EPS_F);
  }
  __syncthreads();

  const int c = tid;
  const float g = ldin(gamma, c, mode), be = ldin(beta, c, mode);
  const size_t rowbase = ((size_t)n * 256 + t * 64) * 256 + c;
#pragma unroll 4
  for (int j = 0; j < 64; ++j) {
    const float v = bs2f(sX[c][j]);
    xn[rowbase + (size_t)j * 256] = f2b((v - smu[j]) * srs[j] * g + be);
  }
}

// ---------------------------------------------------------------------------
// Kernel 2: MFMA qkv GEMM. NEW: transposed-store epilogue — after the K-loop
// the sA/sB LDS (exactly 4 x 64x72 shorts) is repurposed as per-wave slabs;
// bias-added bf16 tiles go in via ds_write_b16, come out as ds_read_b128 +
// global_store_dwordx4 (full 128 B line coverage; was 64 scalar b16 stores).
// ---------------------------------------------------------------------------
__global__ __launch_bounds__(256) void k_qkv(const bf16* __restrict__ A,
                                             const void* __restrict__ Wt,
                                             const void* __restrict__ bias,
                                             bf16* __restrict__ out,
                                             int row_base,
                                             const int* __restrict__ flag) {
  const int mode = flag[0];
  __shared__ short smem[2 * 128 * 72];
  short (*sA)[72] = (short (*)[72])smem;
  short (*sB)[72] = (short (*)[72])(smem + 128 * 72);
  const int row0 = blockIdx.x * 128;
  const int col0 = blockIdx.y * 128;
  const int tid = threadIdx.x;
  const int wid = tid >> 6, lane = tid & 63;
  const int wy = wid >> 1, wx = wid & 1;
  const int l15 = lane & 15, quad = lane >> 4;
  const short* Ab = (const short*)A;

  f32x4 acc[4][4];
#pragma unroll
  for (int i = 0; i < 4; ++i)
#pragma unroll
    for (int j = 0; j < 4; ++j) acc[i][j] = (f32x4){0.f, 0.f, 0.f, 0.f};

  for (int k0 = 0; k0 < 256; k0 += 64) {
    if (k0) __syncthreads();
#pragma unroll
    for (int it = 0; it < 4; ++it) {
      const int id = tid + it * 256;
      const int rr = id >> 3, c8 = (id & 7) * 8;
      *(short8*)&sA[rr][c8] =
          *(const short8*)(Ab + (size_t)(row_base + row0 + rr) * 256 + k0 + c8);
      *(short8*)&sB[rr][c8] = ldin8(Wt, (size_t)(col0 + rr) * 256 + k0 + c8, mode);
    }
    __syncthreads();
#pragma unroll
    for (int kk = 0; kk < 64; kk += 32) {
      short8 af[4], bfv[4];
#pragma unroll
      for (int i = 0; i < 4; ++i)
        af[i] = *(const short8*)&sA[wy * 64 + i * 16 + l15][kk + quad * 8];
#pragma unroll
      for (int j = 0; j < 4; ++j)
        bfv[j] = *(const short8*)&sB[wx * 64 + j * 16 + l15][kk + quad * 8];
#pragma unroll
      for (int i = 0; i < 4; ++i)
#pragma unroll
        for (int j = 0; j < 4; ++j)
          acc[i][j] = __builtin_amdgcn_mfma_f32_16x16x32_bf16(af[i], bfv[j], acc[i][j], 0, 0, 0);
    }
  }

  __syncthreads();  // all waves done reading sA/sB before slab repurpose
  short* slab = smem + wid * (64 * 72);   // per-wave 64x72 (stride 144 B, 16B-mult)
#pragma unroll
  for (int j = 0; j < 4; ++j) {
    const int col = col0 + wx * 64 + j * 16 + l15;
    const float bj = ldin(bias, col, mode);
#pragma unroll
    for (int i = 0; i < 4; ++i)
#pragma unroll
      for (int r = 0; r < 4; ++r)
        slab[(i * 16 + quad * 4 + r) * 72 + j * 16 + l15] = f2bs(acc[i][j][r] + bj);
  }
  asm volatile("s_waitcnt lgkmcnt(0)" ::: "memory");
  {
    const int srow = lane >> 3;        // 0..7
    const int scol = (lane & 7) * 8;   // 0..56
    short* og = (short*)out;
#pragma unroll
    for (int it = 0; it < 8; ++it) {
      const int rloc = it * 8 + srow;
      short8 v = *(const short8*)&slab[rloc * 72 + scol];
      *(short8*)&og[(size_t)(row0 + wy * 64 + rloc) * 768 + col0 + wx * 64 + scol] = v;
    }
  }
}

// ---------------------------------------------------------------------------
// Kernel 3: MFMA attention. NEW: O tile packed through the per-wave sP slab
// -> one ds_read_b128 + one 16 B store per lane per lt (was 8 scalar b16).
// ---------------------------------------------------------------------------
__global__ __launch_bounds__(256) void k_attn(const bf16* __restrict__ qkv,
                                              bf16* __restrict__ aout,
                                              int n_base) {
  const int n_loc = blockIdx.x >> 3, hh = blockIdx.x & 7;
  const int n_glob = n_base + n_loc;
  __shared__ short sK[256][40];
  __shared__ short sVt[32][264];
  __shared__ short sP[4][16][136];   // 136 shorts = 272 B rows (16B-mult)
  const int tid = threadIdx.x;
  const int wid = tid >> 6, lane = tid & 63;
  const int l15 = lane & 15, quad = lane >> 4;
  const short* qg = (const short*)qkv;
  const size_t base = (size_t)n_loc * 256 * 768 + hh * 32;

  for (int c = tid; c < 1024; c += 256) {
    const int m = c >> 2, d0 = (c & 3) * 8;
    *(short8*)&sK[m][d0] = *(const short8*)(qg + base + (size_t)m * 768 + 256 + d0);
    short8 vv = *(const short8*)(qg + base + (size_t)m * 768 + 512 + d0);
#pragma unroll
    for (int j = 0; j < 8; ++j) sVt[d0 + j][m] = vv[j];
  }
  __syncthreads();

  const int R0 = wid * 64;
  const float esc = SCALE_F * LOG2E_F;

  for (int lt = 0; lt < 4; ++lt) {
    const int lrow = R0 + lt * 16;
    const short8 qf = *(const short8*)(qg + base + (size_t)(lrow + l15) * 768 + quad * 8);

    f32x4 sacc[16];
#pragma unroll
    for (int t = 0; t < 16; ++t) {
      sacc[t] = (f32x4){0.f, 0.f, 0.f, 0.f};
      const short8 kf = *(const short8*)&sK[t * 16 + l15][quad * 8];
      sacc[t] = __builtin_amdgcn_mfma_f32_16x16x32_bf16(qf, kf, sacc[t], 0, 0, 0);
    }

    float mx[4] = {-3.0e38f, -3.0e38f, -3.0e38f, -3.0e38f};
#pragma unroll
    for (int t = 0; t < 16; ++t)
#pragma unroll
      for (int r = 0; r < 4; ++r) mx[r] = fmaxf(mx[r], sacc[t][r]);
#pragma unroll
    for (int m = 1; m < 16; m <<= 1)
#pragma unroll
      for (int r = 0; r < 4; ++r) mx[r] = fmaxf(mx[r], __shfl_xor(mx[r], m, 64));
    float sum[4] = {0.f, 0.f, 0.f, 0.f};
#pragma unroll
    for (int t = 0; t < 16; ++t)
#pragma unroll
      for (int r = 0; r < 4; ++r) {
        const float p = exp2f((sacc[t][r] - mx[r]) * esc);
        sacc[t][r] = p;
        sum[r] += p;
      }
#pragma unroll
    for (int m = 1; m < 16; m <<= 1)
#pragma unroll
      for (int r = 0; r < 4; ++r) sum[r] += __shfl_xor(sum[r], m, 64);
    float inv[4];
#pragma unroll
    for (int r = 0; r < 4; ++r) inv[r] = 1.0f / sum[r];

    f32x4 oacc[2] = {(f32x4){0.f, 0.f, 0.f, 0.f}, (f32x4){0.f, 0.f, 0.f, 0.f}};
    for (int half = 0; half < 2; ++half) {
#pragma unroll
      for (int t = 0; t < 8; ++t) {
        const int tt = half * 8 + t;
#pragma unroll
        for (int r = 0; r < 4; ++r)
          sP[wid][quad * 4 + r][t * 16 + l15] = f2bs(sacc[tt][r]);
      }
      asm volatile("s_waitcnt lgkmcnt(0)" ::: "memory");  // writes visible (wave)
#pragma unroll
      for (int kk = 0; kk < 4; ++kk) {
        const short8 pf = *(const short8*)&sP[wid][l15][kk * 32 + quad * 8];
#pragma unroll
        for (int dt = 0; dt < 2; ++dt) {
          const short8 vf =
              *(const short8*)&sVt[dt * 16 + l15][half * 128 + kk * 32 + quad * 8];
          oacc[dt] = __builtin_amdgcn_mfma_f32_16x16x32_bf16(pf, vf, oacc[dt], 0, 0, 0);
        }
      }
      asm volatile("s_waitcnt lgkmcnt(0)" ::: "memory");  // WAR before reuse
    }

    // Pack normalized O through sP; one b128 read + one 16B store per lane.
#pragma unroll
    for (int dt = 0; dt < 2; ++dt)
#pragma unroll
      for (int r = 0; r < 4; ++r)
        sP[wid][quad * 4 + r][dt * 16 + l15] = f2bs(oacc[dt][r] * inv[r]);
    asm volatile("s_waitcnt lgkmcnt(0)" ::: "memory");
    {
      const int rloc = lane >> 2;       // 0..15
      const int c8 = (lane & 3) * 8;    // 0..24
      short8 v = *(const short8*)&sP[wid][rloc][c8];
      short* og = (short*)aout;
      *(short8*)&og[((size_t)n_glob * 256 + lrow + rloc) * 256 + hh * 32 + c8] = v;
    }
    asm volatile("s_waitcnt lgkmcnt(0)" ::: "memory");  // WAR: sP reused next lt
  }
}

// ---------------------------------------------------------------------------
// Kernel 4: MFMA proj GEMM + transposed epilogue (R8-passing, unchanged).
// ---------------------------------------------------------------------------
__global__ __launch_bounds__(256) void k_proj(const bf16* __restrict__ A,
                                              const void* __restrict__ Wp,
                                              const void* __restrict__ bias,
                                              const void* __restrict__ x,
                                              void* __restrict__ out,
                                              const int* __restrict__ flag) {
  const int mode = flag[0];
  __shared__ short sA[128][72];
  __shared__ short sB[128][72];
  __shared__ float sT[4][16][17];
  const int row0 = blockIdx.x * 128;
  const int col0 = blockIdx.y * 128;
  const int tid = threadIdx.x;
  const int wid = tid >> 6, lane = tid & 63;
  const int wy = wid >> 1, wx = wid & 1;
  const int l15 = lane & 15, quad = lane >> 4;
  const short* Ab = (const short*)A;

  f32x4 acc[4][4];
#pragma unroll
  for (int i = 0; i < 4; ++i)
#pragma unroll
    for (int j = 0; j < 4; ++j) acc[i][j] = (f32x4){0.f, 0.f, 0.f, 0.f};

  for (int k0 = 0; k0 < 256; k0 += 64) {
    if (k0) __syncthreads();
#pragma unroll
    for (int it = 0; it < 4; ++it) {
      const int id = tid + it * 256;
      const int rr = id >> 3, c8 = (id & 7) * 8;
      *(short8*)&sA[rr][c8] =
          *(const short8*)(Ab + (size_t)(row0 + rr) * 256 + k0 + c8);
      *(short8*)&sB[rr][c8] = ldin8(Wp, (size_t)(col0 + rr) * 256 + k0 + c8, mode);
    }
    __syncthreads();
#pragma unroll
    for (int kk = 0; kk < 64; kk += 32) {
      short8 af[4], bfv[4];
#pragma unroll
      for (int i = 0; i < 4; ++i)
        af[i] = *(const short8*)&sA[wy * 64 + i * 16 + l15][kk + quad * 8];
#pragma unroll
      for (int j = 0; j < 4; ++j)
        bfv[j] = *(const short8*)&sB[wx * 64 + j * 16 + l15][kk + quad * 8];
#pragma unroll
      for (int i = 0; i < 4; ++i)
#pragma unroll
        for (int j = 0; j < 4; ++j)
          acc[i][j] = __builtin_amdgcn_mfma_f32_16x16x32_bf16(af[i], bfv[j], acc[i][j], 0, 0, 0);
    }
  }

#pragma unroll
  for (int i = 0; i < 4; ++i) {
#pragma unroll
    for (int j = 0; j < 4; ++j) {
#pragma unroll
      for (int r = 0; r < 4; ++r)
        sT[wid][quad * 4 + r][l15] = acc[i][j][r];
      asm volatile("s_waitcnt lgkmcnt(0)" ::: "memory");
#pragma unroll
      for (int r2 = 0; r2 < 4; ++r2) {
        const float v = sT[wid][l15][quad * 4 + r2];
        const int row = row0 + wy * 64 + i * 16 + l15;
        const int c   = col0 + wx * 64 + j * 16 + quad * 4 + r2;
        const int n = row >> 8, l = row & 255;
        const int b = n >> 6, ih = (n >> 3) & 7, iw = n & 7;
        const int tt = l >> 6, rr = (l >> 3) & 7, ss = l & 7;
        const int bt = b * 4 + tt;
        const size_t gaddr = (size_t)bt * 1048576 + (size_t)c * 4096 +
                             (ih * 8 + rr) * 64 + iw * 8 + ss;
        const float o = v + ldin(bias, c, mode) + ldin(x, gaddr, mode);
        stout(out, gaddr, mode, o);
      }
      asm volatile("s_waitcnt lgkmcnt(0)" ::: "memory");
    }
  }
}

// ---------------------------------------------------------------------------
extern "C" void kernel_launch(void* const* d_in, const int* in_sizes, int n_in,
                              void* d_out, int out_size, void* d_ws, size_t ws_size,
                              hipStream_t stream) {
  (void)in_sizes; (void)n_in; (void)out_size;
  const void* x      = d_in[0];
  const void* w_qkv  = d_in[1];
  const void* b_qkv  = d_in[2];
  const void* w_proj = d_in[3];
  const void* b_proj = d_in[4];
  const void* gamma  = d_in[5];
  const void* beta   = d_in[6];

  char* ws = (char*)d_ws;
  int* flag   = (int*)ws;                               // 4 B (+pad to 1 KiB)
  bf16* xnbuf = (bf16*)(ws + 1024);                     // 32768*256*2 = 16 MiB
  bf16* qkvb  = (bf16*)(ws + 1024 + (size_t)16777216);  // full: 48 MiB / chunk: 12.6 MiB

  const size_t need_full = 1024 + (size_t)16777216 + (size_t)32768 * 768 * 2;

  hipLaunchKernelGGL(k_probe, dim3(1), dim3(256), 0, stream, (const float*)x, flag);
  hipLaunchKernelGGL(k_ln, dim3(512), dim3(256), 0, stream, x, gamma, beta, xnbuf, flag);

  if (ws_size >= need_full) {
    hipLaunchKernelGGL(k_qkv, dim3(256, 6), dim3(256), 0, stream,
                       xnbuf, w_qkv, b_qkv, qkvb, 0, flag);
    hipLaunchKernelGGL(k_attn, dim3(1024), dim3(256), 0, stream,
                       qkvb, xnbuf, 0);
  } else {
    for (int c = 0; c < 4; ++c) {
      hipLaunchKernelGGL(k_qkv, dim3(64, 6), dim3(256), 0, stream,
                         xnbuf, w_qkv, b_qkv, qkvb, c * ROWS_CHUNK, flag);
      hipLaunchKernelGGL(k_attn, dim3(NW_CHUNK * 8), dim3(256), 0, stream,
                         qkvb, xnbuf, c * NW_CHUNK);
    }
  }
  hipLaunchKernelGGL(k_proj, dim3(256, 2), dim3(256), 0, stream,
                     xnbuf, w_proj, b_proj, x, d_out, flag);
}